// Round 7
// baseline (1246.594 us; speedup 1.0000x reference)
//
#include <hip/hip_runtime.h>
#include <math.h>

#define N_NODES 50000
#define N_EDGES 1600000
#define F_IN 128
#define C 64
#define EF 64
#define N_GRAPHS 512
#define MLP_DIM 128
#define N_CLASSES 10
#define EPS 1e-5f
#define NB 196            // coarse buckets: dst>>8, 256 nodes each
#define CAPB 16384        // fixed bucket capacity (mean 8192, std ~90 -> safe)
#define CHUNK 4096        // edges per pass-1 block
#define NSLICE 8          // bn-stat atomic slices

typedef __attribute__((ext_vector_type(8))) _Float16 half8;
typedef __attribute__((ext_vector_type(4))) float floatx4;
typedef __attribute__((ext_vector_type(2))) float floatx2;
typedef __attribute__((ext_vector_type(4))) unsigned uintx4;

__device__ __forceinline__ unsigned pkh(float a, float b) {
    // f32 pair -> packed f16 (RTZ), one v_cvt_pkrtz_f16_f32
    auto h = __builtin_amdgcn_cvt_pkrtz(a, b);   // __fp16 ext_vector(2)
    union { decltype(h) h2; unsigned u; } c;
    c.h2 = h;
    return c.u;
}

// ==================== sort pass 1: bin edges into fixed-capacity buckets ====================
__global__ __launch_bounds__(256) void pass1_kernel(const int* __restrict__ src,
                                                    const int* __restrict__ dst,
                                                    int* __restrict__ gcur,
                                                    unsigned* __restrict__ keys) {
    __shared__ int lcnt[NB], lbase[NB], lcnt2[NB];
    int tid = threadIdx.x;
    int e0 = blockIdx.x * CHUNK;
    unsigned k[CHUNK / 256];
    int bk[CHUNK / 256];
    for (int i = tid; i < NB; i += 256) lcnt[i] = 0;
    __syncthreads();
#pragma unroll
    for (int i = 0; i < CHUNK / 256; i++) {
        int e = e0 + i * 256 + tid;
        if (e < N_EDGES) {
            int d = dst[e];
            k[i] = ((unsigned)d << 16) | (unsigned)src[e];
            bk[i] = d >> 8;
            atomicAdd(&lcnt[bk[i]], 1);
        } else bk[i] = -1;
    }
    __syncthreads();
    for (int i = tid; i < NB; i += 256) {
        int c = lcnt[i];
        lbase[i] = c ? atomicAdd(&gcur[i], c) : 0;
        lcnt2[i] = 0;
    }
    __syncthreads();
#pragma unroll
    for (int i = 0; i < CHUNK / 256; i++) {
        if (bk[i] >= 0) {
            int r = atomicAdd(&lcnt2[bk[i]], 1);
            keys[(size_t)bk[i] * CAPB + lbase[bk[i]] + r] = k[i];
        }
    }
}

// ==================== per-node degree + per-bucket padded sums ====================
__global__ __launch_bounds__(256) void node_count_kernel(const unsigned* __restrict__ keys,
                                                         const int* __restrict__ bcnt,
                                                         int* __restrict__ cnt,
                                                         int* __restrict__ bsum) {
    __shared__ int lc[256], rs[256];
    int tid = threadIdx.x, b = blockIdx.x;
    lc[tid] = 0;
    __syncthreads();
    int beg = b * CAPB, end = beg + bcnt[b];
    for (int p = beg + tid; p < end; p += 256)
        atomicAdd(&lc[(keys[p] >> 16) & 255], 1);
    __syncthreads();
    int node = b * 256 + tid;
    int c = (node < N_NODES) ? lc[tid] : 0;
    if (node < N_NODES) cnt[node] = c;
    rs[tid] = (c + 15) & ~15;
    __syncthreads();
    for (int off = 128; off > 0; off >>= 1) {
        if (tid < off) rs[tid] += rs[tid + off];
        __syncthreads();
    }
    if (tid == 0) bsum[b] = rs[0];
}

// exclusive scan of padded bucket sums -> bbase; writes row_start[N_NODES]
__global__ void pscan_kernel(const int* __restrict__ bsum, int* __restrict__ bbase,
                             int* __restrict__ row_start) {
    __shared__ int a[256];
    int tid = threadIdx.x;
    int v = (tid < NB) ? bsum[tid] : 0;
    a[tid] = v;
    __syncthreads();
    for (int off = 1; off < 256; off <<= 1) {
        int t = (tid >= off) ? a[tid - off] : 0;
        __syncthreads();
        a[tid] += t;
        __syncthreads();
    }
    int excl = a[tid] - v;
    if (tid < NB) bbase[tid] = excl;
    if (tid == NB - 1) row_start[N_NODES] = excl + v;
}

// ==================== pass 2: local scan -> row_start, block-local scatter + pad fill ============
__global__ __launch_bounds__(256) void pass2_kernel(const unsigned* __restrict__ keys,
                                                    const int* __restrict__ bcnt,
                                                    const int* __restrict__ cnt,
                                                    const int* __restrict__ bbase,
                                                    int* __restrict__ row_start,
                                                    unsigned short* __restrict__ sorted_src) {
    __shared__ int loc[256], rs[256], cur[256];
    int tid = threadIdx.x, b = blockIdx.x;
    int node = b * 256 + tid;
    int c = (node < N_NODES) ? cnt[node] : 0;
    int pc = (c + 15) & ~15;
    loc[tid] = pc;
    cur[tid] = 0;
    __syncthreads();
    for (int off = 1; off < 256; off <<= 1) {
        int t = (tid >= off) ? loc[tid - off] : 0;
        __syncthreads();
        loc[tid] += t;
        __syncthreads();
    }
    int myrs = bbase[b] + loc[tid] - pc;  // exclusive
    rs[tid] = myrs;
    if (node < N_NODES) row_start[node] = myrs;
    __syncthreads();
    int beg = b * CAPB, end = beg + bcnt[b];
    for (int p = beg + tid; p < end; p += 256) {
        unsigned k = keys[p];
        int lidx = (k >> 16) & 255;
        int r = atomicAdd(&cur[lidx], 1);
        sorted_src[rs[lidx] + r] = (unsigned short)(k & 0xFFFFu);
    }
    __syncthreads();
    if (node < N_NODES) {
        int deg = cur[tid];
        if (deg > 0) {
            unsigned short s0 = sorted_src[myrs];
            for (int p = myrs + deg; p < myrs + pc; p++) sorted_src[p] = s0;  // max idempotent
        }
    }
}

// ============================ fc0: h0 = x @ fc0_w + fc0_b  (+ BN stats for block 0) ============
__global__ __launch_bounds__(256) void fc0_kernel(const float* __restrict__ x,
                                                  const float* __restrict__ w,
                                                  const float* __restrict__ b,
                                                  float* __restrict__ h0,
                                                  float* __restrict__ bns) {
    __shared__ float wl[F_IN * C];  // 32 KiB
    __shared__ __align__(16) float xr[4][F_IN];
    __shared__ float r1[4][64], r2[4][64];
    int tid = threadIdx.x, lane = tid & 63, wid = tid >> 6;
    for (int i = tid; i < F_IN * C; i += 256) wl[i] = w[i];
    __syncthreads();
    float bj = b[lane];
    float s1 = 0.f, s2 = 0.f;
    for (int n = blockIdx.x * 4 + wid; n < N_NODES; n += gridDim.x * 4) {
        xr[wid][lane]      = x[n * F_IN + lane];
        xr[wid][64 + lane] = x[n * F_IN + 64 + lane];
        const float4* x4 = (const float4*)xr[wid];
        float a0 = 0, a1 = 0, a2 = 0, a3 = 0;
#pragma unroll
        for (int k4 = 0; k4 < F_IN / 4; k4++) {
            float4 hv = x4[k4];
            a0 = fmaf(hv.x, wl[(4 * k4 + 0) * C + lane], a0);
            a1 = fmaf(hv.y, wl[(4 * k4 + 1) * C + lane], a1);
            a2 = fmaf(hv.z, wl[(4 * k4 + 2) * C + lane], a2);
            a3 = fmaf(hv.w, wl[(4 * k4 + 3) * C + lane], a3);
        }
        float v = (a0 + a1) + (a2 + a3) + bj;
        h0[n * C + lane] = v;
        s1 += v; s2 += v * v;
    }
    r1[wid][lane] = s1; r2[wid][lane] = s2;
    __syncthreads();
    if (tid < 64) {
        float a  = r1[0][tid] + r1[1][tid] + r1[2][tid] + r1[3][tid];
        float c2 = r2[0][tid] + r2[1][tid] + r2[2][tid] + r2[3][tid];
        int sl = blockIdx.x & (NSLICE - 1);
        atomicAdd(&bns[sl * 128 + tid], a);
        atomicAdd(&bns[sl * 128 + 64 + tid], c2);
    }
}

// ============ ab: fold BN (from bns) + build WA/WB/cAB in LDS, then A/B tables ============
// A = bn(h)@(scale*(w1a-w1b)) + cA (f32),  B = bn(h)@(scale*w1b) + cB (bf16)
__global__ __launch_bounds__(256) void ab_kernel(const float* __restrict__ h, int ldh,
                                                 const float* __restrict__ bns,
                                                 const float* __restrict__ g,
                                                 const float* __restrict__ bb,
                                                 const float* __restrict__ w1,
                                                 const float* __restrict__ b1,
                                                 float* __restrict__ A,
                                                 unsigned short* __restrict__ Bb) {
    __shared__ float wal[64 * 64], wbl[64 * 64];  // 32 KiB
    __shared__ float scale[64], shift[64], cab[128];
    __shared__ __align__(16) float hr[4][64];
    int tid = threadIdx.x, lane = tid & 63, wid = tid >> 6;

    // phase 1: BN scale/shift
    if (tid < 64) {
        float s1v = 0.f, s2v = 0.f;
#pragma unroll
        for (int s = 0; s < NSLICE; s++) { s1v += bns[s * 128 + tid]; s2v += bns[s * 128 + 64 + tid]; }
        float mu  = s1v * (1.0f / N_NODES);
        float var = s2v * (1.0f / N_NODES) - mu * mu;
        float sc  = g[tid] * rsqrtf(var + EPS);
        scale[tid] = sc;
        shift[tid] = bb[tid] - mu * sc;
    }
    // phase 2: unscaled diffs into LDS
    for (int i = tid; i < 4096; i += 256) {
        float wbv = w1[(64 + (i >> 6)) * EF + (i & 63)];
        wal[i] = w1[(i >> 6) * EF + (i & 63)] - wbv;
        wbl[i] = wbv;
    }
    __syncthreads();
    // phase 3: cAB from LDS (threads 0..63 -> cA, 64..127 -> cB)
    if (tid < 128) {
        int j = tid & 63;
        const float* m = (tid < 64) ? wal : wbl;
        float acc = (tid < 64) ? b1[j] : 0.f;
        for (int k = 0; k < 64; k++) acc = fmaf(shift[k], m[k * 64 + j], acc);
        cab[tid] = acc;
    }
    __syncthreads();
    // phase 4: apply scale in place
    for (int i = tid; i < 4096; i += 256) {
        float sc = scale[i >> 6];
        wal[i] *= sc;
        wbl[i] *= sc;
    }
    __syncthreads();

    float ca = cab[lane], cb = cab[64 + lane];
    for (int n = blockIdx.x * 4 + wid; n < N_NODES; n += gridDim.x * 4) {
        hr[wid][lane] = h[(size_t)n * ldh + lane];
        const float4* h4 = (const float4*)hr[wid];
        float accA = ca, accB = cb;
#pragma unroll
        for (int k4 = 0; k4 < 16; k4++) {
            float4 hv = h4[k4];
            accA = fmaf(hv.x, wal[(4 * k4 + 0) * 64 + lane], accA);
            accB = fmaf(hv.x, wbl[(4 * k4 + 0) * 64 + lane], accB);
            accA = fmaf(hv.y, wal[(4 * k4 + 1) * 64 + lane], accA);
            accB = fmaf(hv.y, wbl[(4 * k4 + 1) * 64 + lane], accB);
            accA = fmaf(hv.z, wal[(4 * k4 + 2) * 64 + lane], accA);
            accB = fmaf(hv.z, wbl[(4 * k4 + 2) * 64 + lane], accB);
            accA = fmaf(hv.w, wal[(4 * k4 + 3) * 64 + lane], accA);
            accB = fmaf(hv.w, wbl[(4 * k4 + 3) * 64 + lane], accB);
        }
        A[n * 64 + lane] = accA;
        Bb[n * 64 + lane] = (unsigned short)((__float_as_uint(accB) + 0x8000u) >> 16);
    }
}

// ============ EdgeConv via f16 MFMA, static scheduling, 2-tile ILP, packed math ============
__global__ __launch_bounds__(256, 6) void edge_mfma_kernel(
        const float* __restrict__ A, const unsigned short* __restrict__ Bb,
        const int* __restrict__ row_start, const unsigned short* __restrict__ sorted_src,
        const float* __restrict__ w2, const float* __restrict__ b2,
        float* __restrict__ catp, float* __restrict__ bnsNext) {
    __shared__ float r1[4][64], r2[4][64];
    int tid = threadIdx.x, lane = tid & 63, wid = tid >> 6;
    int kq = (lane >> 4) * 8;  // this lane's k-offset within each 32-chunk
    int cl = lane & 15;

    // w2 fragments (f16), wave-invariant, in registers
    union { half8 h; unsigned u[4]; } bfr[2][4];
#pragma unroll
    for (int kh = 0; kh < 2; kh++)
#pragma unroll
        for (int cb = 0; cb < 4; cb++)
#pragma unroll
            for (int j = 0; j < 4; j++) {
                float w0 = w2[(kh * 32 + kq + 2 * j) * 64 + cb * 16 + cl];
                float w1 = w2[(kh * 32 + kq + 2 * j + 1) * 64 + cb * 16 + cl];
                bfr[kh][cb].u[j] = pkh(w0, w1);
            }
    float b2j = b2[lane];
    float s1 = 0.f, s2 = 0.f;
    const floatx2 zero2 = {0.f, 0.f};

    for (int n = blockIdx.x * 4 + wid; n < N_NODES; n += gridDim.x * 4) {
        int beg = row_start[n], end = row_start[n + 1];
        const float* arow = A + (size_t)n * 64 + kq;
        floatx4 t0 = *(const floatx4*)(arow);
        floatx4 t1 = *(const floatx4*)(arow + 4);
        floatx4 t2 = *(const floatx4*)(arow + 32);
        floatx4 t3 = *(const floatx4*)(arow + 36);
        floatx2 aj0[4], aj1[4];
        aj0[0] = floatx2{t0.x, t0.y}; aj0[1] = floatx2{t0.z, t0.w};
        aj0[2] = floatx2{t1.x, t1.y}; aj0[3] = floatx2{t1.z, t1.w};
        aj1[0] = floatx2{t2.x, t2.y}; aj1[1] = floatx2{t2.z, t2.w};
        aj1[2] = floatx2{t3.x, t3.y}; aj1[3] = floatx2{t3.z, t3.w};
        floatx4 rmax0 = {-INFINITY, -INFINITY, -INFINITY, -INFINITY};
        floatx4 rmax1 = rmax0, rmax2 = rmax0, rmax3 = rmax0;

        auto tile = [&](uintx4 u0, uintx4 u1) {
            union { half8 h; unsigned u[4]; } a0, a1;
#pragma unroll
            for (int j = 0; j < 4; j++) {
                floatx2 s0 = floatx2{__uint_as_float(u0[j] << 16),
                                     __uint_as_float(u0[j] & 0xFFFF0000u)} + aj0[j];
                floatx2 sx = floatx2{__uint_as_float(u1[j] << 16),
                                     __uint_as_float(u1[j] & 0xFFFF0000u)} + aj1[j];
                s0 = __builtin_elementwise_max(s0, zero2);
                sx = __builtin_elementwise_max(sx, zero2);
                a0.u[j] = pkh(s0.x, s0.y);
                a1.u[j] = pkh(sx.x, sx.y);
            }
            floatx4 acc0 = {0.f, 0.f, 0.f, 0.f}, acc1 = acc0, acc2 = acc0, acc3 = acc0;
            acc0 = __builtin_amdgcn_mfma_f32_16x16x32_f16(a0.h, bfr[0][0].h, acc0, 0, 0, 0);
            acc1 = __builtin_amdgcn_mfma_f32_16x16x32_f16(a0.h, bfr[0][1].h, acc1, 0, 0, 0);
            acc2 = __builtin_amdgcn_mfma_f32_16x16x32_f16(a0.h, bfr[0][2].h, acc2, 0, 0, 0);
            acc3 = __builtin_amdgcn_mfma_f32_16x16x32_f16(a0.h, bfr[0][3].h, acc3, 0, 0, 0);
            acc0 = __builtin_amdgcn_mfma_f32_16x16x32_f16(a1.h, bfr[1][0].h, acc0, 0, 0, 0);
            acc1 = __builtin_amdgcn_mfma_f32_16x16x32_f16(a1.h, bfr[1][1].h, acc1, 0, 0, 0);
            acc2 = __builtin_amdgcn_mfma_f32_16x16x32_f16(a1.h, bfr[1][2].h, acc2, 0, 0, 0);
            acc3 = __builtin_amdgcn_mfma_f32_16x16x32_f16(a1.h, bfr[1][3].h, acc3, 0, 0, 0);
            rmax0 = __builtin_elementwise_max(rmax0, acc0);
            rmax1 = __builtin_elementwise_max(rmax1, acc1);
            rmax2 = __builtin_elementwise_max(rmax2, acc2);
            rmax3 = __builtin_elementwise_max(rmax3, acc3);
        };
        auto gather = [&](int p, uintx4& u0, uintx4& u1) {
            int srcm = sorted_src[p + cl];
            const unsigned short* brow = Bb + (size_t)srcm * 64 + kq;
            u0 = *(const uintx4*)(brow);
            u1 = *(const uintx4*)(brow + 32);
        };

        int p0 = beg;
        for (; p0 + 32 <= end; p0 += 32) {   // two tiles per iter: both gathers in flight
            uintx4 x0, x1, y0, y1;
            gather(p0, x0, x1);
            gather(p0 + 16, y0, y1);
            tile(x0, x1);
            tile(y0, y1);
        }
        if (p0 < end) {                       // odd-tile remainder
            uintx4 x0, x1;
            gather(p0, x0, x1);
            tile(x0, x1);
        }

        float v0 = fmaxf(fmaxf(rmax0.x, rmax0.y), fmaxf(rmax0.z, rmax0.w));
        float v1 = fmaxf(fmaxf(rmax1.x, rmax1.y), fmaxf(rmax1.z, rmax1.w));
        float v2 = fmaxf(fmaxf(rmax2.x, rmax2.y), fmaxf(rmax2.z, rmax2.w));
        float v3 = fmaxf(fmaxf(rmax3.x, rmax3.y), fmaxf(rmax3.z, rmax3.w));
        v0 = fmaxf(v0, __shfl_xor(v0, 16)); v0 = fmaxf(v0, __shfl_xor(v0, 32));
        v1 = fmaxf(v1, __shfl_xor(v1, 16)); v1 = fmaxf(v1, __shfl_xor(v1, 32));
        v2 = fmaxf(v2, __shfl_xor(v2, 16)); v2 = fmaxf(v2, __shfl_xor(v2, 32));
        v3 = fmaxf(v3, __shfl_xor(v3, 16)); v3 = fmaxf(v3, __shfl_xor(v3, 32));
        float vs = (lane & 32) ? ((lane & 16) ? v3 : v2) : ((lane & 16) ? v1 : v0);
        float v = fmaxf(vs + b2j, 0.f);  // -inf (empty node) -> 0; folds where(isfinite)+relu
        catp[(size_t)n * 64 + lane] = v;
        s1 += v; s2 += v * v;
    }

    if (bnsNext) {
        r1[wid][lane] = s1; r2[wid][lane] = s2;
        __syncthreads();
        if (tid < 64) {
            float a  = r1[0][tid] + r1[1][tid] + r1[2][tid] + r1[3][tid];
            float c2 = r2[0][tid] + r2[1][tid] + r2[2][tid] + r2[3][tid];
            int sl = blockIdx.x & (NSLICE - 1);
            atomicAdd(&bnsNext[sl * 128 + tid], a);
            atomicAdd(&bnsNext[sl * 128 + 64 + tid], c2);
        }
    }
}

// ============================ fused graph mean pool + MLP head + log_softmax ============================
__global__ __launch_bounds__(192) void poolhead_kernel(const float* __restrict__ cat0,
                                                       const float* __restrict__ cat1,
                                                       const float* __restrict__ cat2,
                                                       const int* __restrict__ batch,
                                                       const float* __restrict__ fc1w,
                                                       const float* __restrict__ fc1b,
                                                       const float* __restrict__ fc2w,
                                                       const float* __restrict__ fc2b,
                                                       float* __restrict__ out) {
    __shared__ int se[2];
    __shared__ float p[192];
    __shared__ float hid[128];
    __shared__ float z[10];
    __shared__ float lse;
    int g = blockIdx.x, tid = threadIdx.x;  // 192 threads
    if (tid < 2) {
        int target = g + tid;
        int lo = 0, hi = N_NODES;
        while (lo < hi) { int mid = (lo + hi) >> 1; if (batch[mid] < target) lo = mid + 1; else hi = mid; }
        se[tid] = lo;
    }
    __syncthreads();
    int s = se[0], e = se[1];
    const float* plane = (tid < 64) ? cat0 : ((tid < 128) ? cat1 : cat2);
    int col = tid & 63;
    float acc = 0.f;
    for (int r = s; r < e; r++) acc += plane[(size_t)r * 64 + col];
    float denom = (e > s) ? (float)(e - s) : 1.0f;
    p[tid] = acc / denom;
    __syncthreads();
    if (tid < MLP_DIM) {
        float a = fc1b[tid];
        for (int k = 0; k < 192; k++) a = fmaf(p[k], fc1w[k * 128 + tid], a);
        hid[tid] = fmaxf(a, 0.f);
    }
    __syncthreads();
    if (tid < N_CLASSES) {
        float a = fc2b[tid];
        for (int k = 0; k < 128; k++) a = fmaf(hid[k], fc2w[k * 10 + tid], a);
        z[tid] = a;
    }
    __syncthreads();
    if (tid == 0) {
        float m = z[0];
        for (int i = 1; i < 10; i++) m = fmaxf(m, z[i]);
        float sm = 0.f;
        for (int i = 0; i < 10; i++) sm += expf(z[i] - m);
        lse = m + logf(sm);
    }
    __syncthreads();
    if (tid < N_CLASSES) out[g * 10 + tid] = z[tid] - lse;
}

// ============================ launch ============================
extern "C" void kernel_launch(void* const* d_in, const int* in_sizes, int n_in,
                              void* d_out, int out_size, void* d_ws, size_t ws_size,
                              hipStream_t stream) {
    (void)in_sizes; (void)n_in; (void)out_size; (void)ws_size;
    const float* x    = (const float*)d_in[0];
    const int*   ei   = (const int*)d_in[1];
    const int*   batch= (const int*)d_in[2];
    const float* fc0w = (const float*)d_in[3];
    const float* fc0b = (const float*)d_in[4];
    const float* fc1w = (const float*)d_in[5];
    const float* fc1b = (const float*)d_in[6];
    const float* fc2w = (const float*)d_in[7];
    const float* fc2b = (const float*)d_in[8];
    const int* src = ei;
    const int* dst = ei + N_EDGES;
    float* out = (float*)d_out;

    char* w = (char*)d_ws;
    size_t off = 0;
    auto alloc = [&](size_t bytes) -> void* {
        void* p = w + off;
        off = (off + bytes + 255) & ~(size_t)255;
        return p;
    };
    const size_t MAX_PAD_EDGES = (size_t)N_EDGES + 16 * (size_t)N_NODES;

    // zeroed-every-launch block: gcur[NB] | bns[3][NSLICE][128]
    char* zbase = (char*)alloc(1024 + 3 * NSLICE * 128 * 4);
    int*   gcur   = (int*)zbase;                     // NB ints (bucket cursors = final counts)
    float* bnsAll = (float*)(zbase + 1024);          // 3 * NSLICE * 128 floats
    const size_t ZBYTES = 1024 + 3 * NSLICE * 128 * 4;

    float* cat0    = (float*)alloc((size_t)N_NODES * 64 * 4);    // 12.8 MB each plane
    float* cat1    = (float*)alloc((size_t)N_NODES * 64 * 4);
    float* cat2    = (float*)alloc((size_t)N_NODES * 64 * 4);
    float* h0      = (float*)alloc((size_t)N_NODES * 64 * 4);    // 12.8 MB
    float* Ae      = (float*)alloc((size_t)N_NODES * 64 * 4);    // 12.8 MB
    unsigned short* Be = (unsigned short*)alloc((size_t)N_NODES * 64 * 2);  // 6.4 MB (bf16)
    unsigned* keys = (unsigned*)alloc((size_t)NB * CAPB * 4);    // 12.85 MB
    unsigned short* sorted_src = (unsigned short*)alloc(MAX_PAD_EDGES * 2);  // 4.8 MB
    int*   cnt     = (int*)alloc((size_t)N_NODES * 4);
    int*   row_start = (int*)alloc((size_t)(N_NODES + 1) * 4);
    int*   bsum    = (int*)alloc(NB * 4);
    int*   bbase   = (int*)alloc(NB * 4);

    (void)hipMemsetAsync(zbase, 0, ZBYTES, stream);

    // --- two-level counting sort (fixed-capacity buckets): edges -> padded CSR by dst ---
    pass1_kernel<<<(N_EDGES + CHUNK - 1) / CHUNK, 256, 0, stream>>>(src, dst, gcur, keys);
    node_count_kernel<<<NB, 256, 0, stream>>>(keys, gcur, cnt, bsum);
    pscan_kernel<<<1, 256, 0, stream>>>(bsum, bbase, row_start);
    pass2_kernel<<<NB, 256, 0, stream>>>(keys, gcur, cnt, bbase, row_start, sorted_src);

    fc0_kernel<<<1024, 256, 0, stream>>>(x, fc0w, fc0b, h0, bnsAll);

    float* planes[3] = {cat0, cat1, cat2};
    for (int blk = 0; blk < 3; blk++) {
        const float* g  = (const float*)d_in[9 + 6 * blk];
        const float* bb = (const float*)d_in[10 + 6 * blk];
        const float* w1 = (const float*)d_in[11 + 6 * blk];
        const float* b1 = (const float*)d_in[12 + 6 * blk];
        const float* w2 = (const float*)d_in[13 + 6 * blk];
        const float* b2 = (const float*)d_in[14 + 6 * blk];
        const float* hsrc = (blk == 0) ? h0 : planes[blk - 1];

        ab_kernel<<<1024, 256, 0, stream>>>(hsrc, 64, bnsAll + blk * NSLICE * 128,
                                            g, bb, w1, b1, Ae, Be);
        edge_mfma_kernel<<<2048, 256, 0, stream>>>(
            Ae, Be, row_start, sorted_src, w2, b2, planes[blk],
            (blk < 2) ? (bnsAll + (blk + 1) * NSLICE * 128) : nullptr);
    }

    poolhead_kernel<<<N_GRAPHS, 192, 0, stream>>>(cat0, cat1, cat2, batch,
                                                  fc1w, fc1b, fc2w, fc2b, out);
}

// Round 8
// 466.004 us; speedup vs baseline: 2.6751x; 2.6751x over previous
//
#include <hip/hip_runtime.h>
#include <math.h>

#define N_NODES 50000
#define N_EDGES 1600000
#define F_IN 128
#define C 64
#define EF 64
#define N_GRAPHS 512
#define MLP_DIM 128
#define N_CLASSES 10
#define EPS 1e-5f
#define NB 196            // coarse buckets: dst>>8, 256 nodes each
#define CAPB 16384        // fixed bucket capacity (mean 8192, std ~90 -> safe)
#define CHUNK 4096        // edges per pass-1 block
#define NSLICE 8          // bn-stat atomic slices

typedef __attribute__((ext_vector_type(8))) _Float16 half8;
typedef __attribute__((ext_vector_type(4))) float floatx4;
typedef __attribute__((ext_vector_type(2))) float floatx2;
typedef __attribute__((ext_vector_type(4))) unsigned uintx4;

__device__ __forceinline__ unsigned pkh(float a, float b) {
    // f32 pair -> packed f16 (RTZ), one v_cvt_pkrtz_f16_f32
    auto h = __builtin_amdgcn_cvt_pkrtz(a, b);   // __fp16 ext_vector(2)
    union { decltype(h) h2; unsigned u; } c;
    c.h2 = h;
    return c.u;
}

// ==================== sort pass 1: bin edges into fixed-capacity buckets ====================
__global__ __launch_bounds__(256) void pass1_kernel(const int* __restrict__ src,
                                                    const int* __restrict__ dst,
                                                    int* __restrict__ gcur,
                                                    unsigned* __restrict__ keys) {
    __shared__ int lcnt[NB], lbase[NB], lcnt2[NB];
    int tid = threadIdx.x;
    int e0 = blockIdx.x * CHUNK;
    unsigned k[CHUNK / 256];
    int bk[CHUNK / 256];
    for (int i = tid; i < NB; i += 256) lcnt[i] = 0;
    __syncthreads();
#pragma unroll
    for (int i = 0; i < CHUNK / 256; i++) {
        int e = e0 + i * 256 + tid;
        if (e < N_EDGES) {
            int d = dst[e];
            k[i] = ((unsigned)d << 16) | (unsigned)src[e];
            bk[i] = d >> 8;
            atomicAdd(&lcnt[bk[i]], 1);
        } else bk[i] = -1;
    }
    __syncthreads();
    for (int i = tid; i < NB; i += 256) {
        int c = lcnt[i];
        lbase[i] = c ? atomicAdd(&gcur[i], c) : 0;
        lcnt2[i] = 0;
    }
    __syncthreads();
#pragma unroll
    for (int i = 0; i < CHUNK / 256; i++) {
        if (bk[i] >= 0) {
            int r = atomicAdd(&lcnt2[bk[i]], 1);
            keys[(size_t)bk[i] * CAPB + lbase[bk[i]] + r] = k[i];
        }
    }
}

// ==================== per-node degree + per-bucket padded sums ====================
__global__ __launch_bounds__(256) void node_count_kernel(const unsigned* __restrict__ keys,
                                                         const int* __restrict__ bcnt,
                                                         int* __restrict__ cnt,
                                                         int* __restrict__ bsum) {
    __shared__ int lc[256], rs[256];
    int tid = threadIdx.x, b = blockIdx.x;
    lc[tid] = 0;
    __syncthreads();
    int beg = b * CAPB, end = beg + bcnt[b];
    for (int p = beg + tid; p < end; p += 256)
        atomicAdd(&lc[(keys[p] >> 16) & 255], 1);
    __syncthreads();
    int node = b * 256 + tid;
    int c = (node < N_NODES) ? lc[tid] : 0;
    if (node < N_NODES) cnt[node] = c;
    rs[tid] = (c + 15) & ~15;
    __syncthreads();
    for (int off = 128; off > 0; off >>= 1) {
        if (tid < off) rs[tid] += rs[tid + off];
        __syncthreads();
    }
    if (tid == 0) bsum[b] = rs[0];
}

// exclusive scan of padded bucket sums -> bbase; writes row_start[N_NODES]
__global__ void pscan_kernel(const int* __restrict__ bsum, int* __restrict__ bbase,
                             int* __restrict__ row_start) {
    __shared__ int a[256];
    int tid = threadIdx.x;
    int v = (tid < NB) ? bsum[tid] : 0;
    a[tid] = v;
    __syncthreads();
    for (int off = 1; off < 256; off <<= 1) {
        int t = (tid >= off) ? a[tid - off] : 0;
        __syncthreads();
        a[tid] += t;
        __syncthreads();
    }
    int excl = a[tid] - v;
    if (tid < NB) bbase[tid] = excl;
    if (tid == NB - 1) row_start[N_NODES] = excl + v;
}

// ==================== pass 2: local scan -> row_start, block-local scatter + pad fill ============
__global__ __launch_bounds__(256) void pass2_kernel(const unsigned* __restrict__ keys,
                                                    const int* __restrict__ bcnt,
                                                    const int* __restrict__ cnt,
                                                    const int* __restrict__ bbase,
                                                    int* __restrict__ row_start,
                                                    unsigned short* __restrict__ sorted_src) {
    __shared__ int loc[256], rs[256], cur[256];
    int tid = threadIdx.x, b = blockIdx.x;
    int node = b * 256 + tid;
    int c = (node < N_NODES) ? cnt[node] : 0;
    int pc = (c + 15) & ~15;
    loc[tid] = pc;
    cur[tid] = 0;
    __syncthreads();
    for (int off = 1; off < 256; off <<= 1) {
        int t = (tid >= off) ? loc[tid - off] : 0;
        __syncthreads();
        loc[tid] += t;
        __syncthreads();
    }
    int myrs = bbase[b] + loc[tid] - pc;  // exclusive
    rs[tid] = myrs;
    if (node < N_NODES) row_start[node] = myrs;
    __syncthreads();
    int beg = b * CAPB, end = beg + bcnt[b];
    for (int p = beg + tid; p < end; p += 256) {
        unsigned k = keys[p];
        int lidx = (k >> 16) & 255;
        int r = atomicAdd(&cur[lidx], 1);
        sorted_src[rs[lidx] + r] = (unsigned short)(k & 0xFFFFu);
    }
    __syncthreads();
    if (node < N_NODES) {
        int deg = cur[tid];
        if (deg > 0) {
            unsigned short s0 = sorted_src[myrs];
            for (int p = myrs + deg; p < myrs + pc; p++) sorted_src[p] = s0;  // max idempotent
        }
    }
}

// ============================ fc0: h0 = x @ fc0_w + fc0_b  (+ BN stats for block 0) ============
__global__ __launch_bounds__(256) void fc0_kernel(const float* __restrict__ x,
                                                  const float* __restrict__ w,
                                                  const float* __restrict__ b,
                                                  float* __restrict__ h0,
                                                  float* __restrict__ bns) {
    __shared__ float wl[F_IN * C];  // 32 KiB
    __shared__ __align__(16) float xr[4][F_IN];
    __shared__ float r1[4][64], r2[4][64];
    int tid = threadIdx.x, lane = tid & 63, wid = tid >> 6;
    for (int i = tid; i < F_IN * C; i += 256) wl[i] = w[i];
    __syncthreads();
    float bj = b[lane];
    float s1 = 0.f, s2 = 0.f;
    for (int n = blockIdx.x * 4 + wid; n < N_NODES; n += gridDim.x * 4) {
        xr[wid][lane]      = x[n * F_IN + lane];
        xr[wid][64 + lane] = x[n * F_IN + 64 + lane];
        const float4* x4 = (const float4*)xr[wid];
        float a0 = 0, a1 = 0, a2 = 0, a3 = 0;
#pragma unroll
        for (int k4 = 0; k4 < F_IN / 4; k4++) {
            float4 hv = x4[k4];
            a0 = fmaf(hv.x, wl[(4 * k4 + 0) * C + lane], a0);
            a1 = fmaf(hv.y, wl[(4 * k4 + 1) * C + lane], a1);
            a2 = fmaf(hv.z, wl[(4 * k4 + 2) * C + lane], a2);
            a3 = fmaf(hv.w, wl[(4 * k4 + 3) * C + lane], a3);
        }
        float v = (a0 + a1) + (a2 + a3) + bj;
        h0[n * C + lane] = v;
        s1 += v; s2 += v * v;
    }
    r1[wid][lane] = s1; r2[wid][lane] = s2;
    __syncthreads();
    if (tid < 64) {
        float a  = r1[0][tid] + r1[1][tid] + r1[2][tid] + r1[3][tid];
        float c2 = r2[0][tid] + r2[1][tid] + r2[2][tid] + r2[3][tid];
        int sl = blockIdx.x & (NSLICE - 1);
        atomicAdd(&bns[sl * 128 + tid], a);
        atomicAdd(&bns[sl * 128 + 64 + tid], c2);
    }
}

// ============ ab: fold BN (from bns) + build WA/WB/cAB in LDS, then A/B tables ============
__global__ __launch_bounds__(256) void ab_kernel(const float* __restrict__ h, int ldh,
                                                 const float* __restrict__ bns,
                                                 const float* __restrict__ g,
                                                 const float* __restrict__ bb,
                                                 const float* __restrict__ w1,
                                                 const float* __restrict__ b1,
                                                 float* __restrict__ A,
                                                 unsigned short* __restrict__ Bb) {
    __shared__ float wal[64 * 64], wbl[64 * 64];  // 32 KiB
    __shared__ float scale[64], shift[64], cab[128];
    __shared__ __align__(16) float hr[4][64];
    int tid = threadIdx.x, lane = tid & 63, wid = tid >> 6;

    // phase 1: BN scale/shift
    if (tid < 64) {
        float s1v = 0.f, s2v = 0.f;
#pragma unroll
        for (int s = 0; s < NSLICE; s++) { s1v += bns[s * 128 + tid]; s2v += bns[s * 128 + 64 + tid]; }
        float mu  = s1v * (1.0f / N_NODES);
        float var = s2v * (1.0f / N_NODES) - mu * mu;
        float sc  = g[tid] * rsqrtf(var + EPS);
        scale[tid] = sc;
        shift[tid] = bb[tid] - mu * sc;
    }
    // phase 2: unscaled diffs into LDS
    for (int i = tid; i < 4096; i += 256) {
        float wbv = w1[(64 + (i >> 6)) * EF + (i & 63)];
        wal[i] = w1[(i >> 6) * EF + (i & 63)] - wbv;
        wbl[i] = wbv;
    }
    __syncthreads();
    // phase 3: cAB from LDS (threads 0..63 -> cA, 64..127 -> cB)
    if (tid < 128) {
        int j = tid & 63;
        const float* m = (tid < 64) ? wal : wbl;
        float acc = (tid < 64) ? b1[j] : 0.f;
        for (int k = 0; k < 64; k++) acc = fmaf(shift[k], m[k * 64 + j], acc);
        cab[tid] = acc;
    }
    __syncthreads();
    // phase 4: apply scale in place
    for (int i = tid; i < 4096; i += 256) {
        float sc = scale[i >> 6];
        wal[i] *= sc;
        wbl[i] *= sc;
    }
    __syncthreads();

    float ca = cab[lane], cb = cab[64 + lane];
    for (int n = blockIdx.x * 4 + wid; n < N_NODES; n += gridDim.x * 4) {
        hr[wid][lane] = h[(size_t)n * ldh + lane];
        const float4* h4 = (const float4*)hr[wid];
        float accA = ca, accB = cb;
#pragma unroll
        for (int k4 = 0; k4 < 16; k4++) {
            float4 hv = h4[k4];
            accA = fmaf(hv.x, wal[(4 * k4 + 0) * 64 + lane], accA);
            accB = fmaf(hv.x, wbl[(4 * k4 + 0) * 64 + lane], accB);
            accA = fmaf(hv.y, wal[(4 * k4 + 1) * 64 + lane], accA);
            accB = fmaf(hv.y, wbl[(4 * k4 + 1) * 64 + lane], accB);
            accA = fmaf(hv.z, wal[(4 * k4 + 2) * 64 + lane], accA);
            accB = fmaf(hv.z, wbl[(4 * k4 + 2) * 64 + lane], accB);
            accA = fmaf(hv.w, wal[(4 * k4 + 3) * 64 + lane], accA);
            accB = fmaf(hv.w, wbl[(4 * k4 + 3) * 64 + lane], accB);
        }
        A[n * 64 + lane] = accA;
        Bb[n * 64 + lane] = (unsigned short)((__float_as_uint(accB) + 0x8000u) >> 16);
    }
}

// ============ EdgeConv via f16 MFMA, static scheduling, 2-tile ILP, packed math ============
// launch_bounds (256,4): VGPR cap 128 — kernel fits ~64, NO spill. (256,6) forced 85-reg cap
// and spilled the hot loop to scratch: 729 MB fetch/dispatch, 6x slowdown (R7 post-mortem).
__global__ __launch_bounds__(256, 4) void edge_mfma_kernel(
        const float* __restrict__ A, const unsigned short* __restrict__ Bb,
        const int* __restrict__ row_start, const unsigned short* __restrict__ sorted_src,
        const float* __restrict__ w2, const float* __restrict__ b2,
        float* __restrict__ catp, float* __restrict__ bnsNext) {
    __shared__ float r1[4][64], r2[4][64];
    int tid = threadIdx.x, lane = tid & 63, wid = tid >> 6;
    int kq = (lane >> 4) * 8;  // this lane's k-offset within each 32-chunk
    int cl = lane & 15;

    // w2 fragments (f16), wave-invariant, in registers
    union { half8 h; unsigned u[4]; } bfr[2][4];
#pragma unroll
    for (int kh = 0; kh < 2; kh++)
#pragma unroll
        for (int cb = 0; cb < 4; cb++)
#pragma unroll
            for (int j = 0; j < 4; j++) {
                float w0 = w2[(kh * 32 + kq + 2 * j) * 64 + cb * 16 + cl];
                float w1 = w2[(kh * 32 + kq + 2 * j + 1) * 64 + cb * 16 + cl];
                bfr[kh][cb].u[j] = pkh(w0, w1);
            }
    float b2j = b2[lane];
    float s1 = 0.f, s2 = 0.f;
    const floatx2 zero2 = {0.f, 0.f};

    for (int n = blockIdx.x * 4 + wid; n < N_NODES; n += gridDim.x * 4) {
        int beg = row_start[n], end = row_start[n + 1];
        const float* arow = A + (size_t)n * 64 + kq;
        floatx4 t0 = *(const floatx4*)(arow);
        floatx4 t1 = *(const floatx4*)(arow + 4);
        floatx4 t2 = *(const floatx4*)(arow + 32);
        floatx4 t3 = *(const floatx4*)(arow + 36);
        floatx2 aj0[4], aj1[4];
        aj0[0] = floatx2{t0.x, t0.y}; aj0[1] = floatx2{t0.z, t0.w};
        aj0[2] = floatx2{t1.x, t1.y}; aj0[3] = floatx2{t1.z, t1.w};
        aj1[0] = floatx2{t2.x, t2.y}; aj1[1] = floatx2{t2.z, t2.w};
        aj1[2] = floatx2{t3.x, t3.y}; aj1[3] = floatx2{t3.z, t3.w};
        floatx4 rmax0 = {-INFINITY, -INFINITY, -INFINITY, -INFINITY};
        floatx4 rmax1 = rmax0, rmax2 = rmax0, rmax3 = rmax0;

        auto tile = [&](uintx4 u0, uintx4 u1) {
            union { half8 h; unsigned u[4]; } a0, a1;
#pragma unroll
            for (int j = 0; j < 4; j++) {
                floatx2 s0 = floatx2{__uint_as_float(u0[j] << 16),
                                     __uint_as_float(u0[j] & 0xFFFF0000u)} + aj0[j];
                floatx2 sx = floatx2{__uint_as_float(u1[j] << 16),
                                     __uint_as_float(u1[j] & 0xFFFF0000u)} + aj1[j];
                s0 = __builtin_elementwise_max(s0, zero2);
                sx = __builtin_elementwise_max(sx, zero2);
                a0.u[j] = pkh(s0.x, s0.y);
                a1.u[j] = pkh(sx.x, sx.y);
            }
            floatx4 acc0 = {0.f, 0.f, 0.f, 0.f}, acc1 = acc0, acc2 = acc0, acc3 = acc0;
            acc0 = __builtin_amdgcn_mfma_f32_16x16x32_f16(a0.h, bfr[0][0].h, acc0, 0, 0, 0);
            acc1 = __builtin_amdgcn_mfma_f32_16x16x32_f16(a0.h, bfr[0][1].h, acc1, 0, 0, 0);
            acc2 = __builtin_amdgcn_mfma_f32_16x16x32_f16(a0.h, bfr[0][2].h, acc2, 0, 0, 0);
            acc3 = __builtin_amdgcn_mfma_f32_16x16x32_f16(a0.h, bfr[0][3].h, acc3, 0, 0, 0);
            acc0 = __builtin_amdgcn_mfma_f32_16x16x32_f16(a1.h, bfr[1][0].h, acc0, 0, 0, 0);
            acc1 = __builtin_amdgcn_mfma_f32_16x16x32_f16(a1.h, bfr[1][1].h, acc1, 0, 0, 0);
            acc2 = __builtin_amdgcn_mfma_f32_16x16x32_f16(a1.h, bfr[1][2].h, acc2, 0, 0, 0);
            acc3 = __builtin_amdgcn_mfma_f32_16x16x32_f16(a1.h, bfr[1][3].h, acc3, 0, 0, 0);
            rmax0 = __builtin_elementwise_max(rmax0, acc0);
            rmax1 = __builtin_elementwise_max(rmax1, acc1);
            rmax2 = __builtin_elementwise_max(rmax2, acc2);
            rmax3 = __builtin_elementwise_max(rmax3, acc3);
        };
        auto gather = [&](int p, uintx4& u0, uintx4& u1) {
            int srcm = sorted_src[p + cl];
            const unsigned short* brow = Bb + (size_t)srcm * 64 + kq;
            u0 = *(const uintx4*)(brow);
            u1 = *(const uintx4*)(brow + 32);
        };

        int p0 = beg;
        for (; p0 + 32 <= end; p0 += 32) {   // two tiles per iter: both gathers in flight
            uintx4 x0, x1, y0, y1;
            gather(p0, x0, x1);
            gather(p0 + 16, y0, y1);
            tile(x0, x1);
            tile(y0, y1);
        }
        if (p0 < end) {                       // odd-tile remainder
            uintx4 x0, x1;
            gather(p0, x0, x1);
            tile(x0, x1);
        }

        float v0 = fmaxf(fmaxf(rmax0.x, rmax0.y), fmaxf(rmax0.z, rmax0.w));
        float v1 = fmaxf(fmaxf(rmax1.x, rmax1.y), fmaxf(rmax1.z, rmax1.w));
        float v2 = fmaxf(fmaxf(rmax2.x, rmax2.y), fmaxf(rmax2.z, rmax2.w));
        float v3 = fmaxf(fmaxf(rmax3.x, rmax3.y), fmaxf(rmax3.z, rmax3.w));
        v0 = fmaxf(v0, __shfl_xor(v0, 16)); v0 = fmaxf(v0, __shfl_xor(v0, 32));
        v1 = fmaxf(v1, __shfl_xor(v1, 16)); v1 = fmaxf(v1, __shfl_xor(v1, 32));
        v2 = fmaxf(v2, __shfl_xor(v2, 16)); v2 = fmaxf(v2, __shfl_xor(v2, 32));
        v3 = fmaxf(v3, __shfl_xor(v3, 16)); v3 = fmaxf(v3, __shfl_xor(v3, 32));
        float vs = (lane & 32) ? ((lane & 16) ? v3 : v2) : ((lane & 16) ? v1 : v0);
        float v = fmaxf(vs + b2j, 0.f);  // -inf (empty node) -> 0; folds where(isfinite)+relu
        catp[(size_t)n * 64 + lane] = v;
        s1 += v; s2 += v * v;
    }

    if (bnsNext) {
        r1[wid][lane] = s1; r2[wid][lane] = s2;
        __syncthreads();
        if (tid < 64) {
            float a  = r1[0][tid] + r1[1][tid] + r1[2][tid] + r1[3][tid];
            float c2 = r2[0][tid] + r2[1][tid] + r2[2][tid] + r2[3][tid];
            int sl = blockIdx.x & (NSLICE - 1);
            atomicAdd(&bnsNext[sl * 128 + tid], a);
            atomicAdd(&bnsNext[sl * 128 + 64 + tid], c2);
        }
    }
}

// ============================ fused graph mean pool + MLP head + log_softmax ============================
__global__ __launch_bounds__(192) void poolhead_kernel(const float* __restrict__ cat0,
                                                       const float* __restrict__ cat1,
                                                       const float* __restrict__ cat2,
                                                       const int* __restrict__ batch,
                                                       const float* __restrict__ fc1w,
                                                       const float* __restrict__ fc1b,
                                                       const float* __restrict__ fc2w,
                                                       const float* __restrict__ fc2b,
                                                       float* __restrict__ out) {
    __shared__ int se[2];
    __shared__ float p[192];
    __shared__ float hid[128];
    __shared__ float z[10];
    __shared__ float lse;
    int g = blockIdx.x, tid = threadIdx.x;  // 192 threads
    if (tid < 2) {
        int target = g + tid;
        int lo = 0, hi = N_NODES;
        while (lo < hi) { int mid = (lo + hi) >> 1; if (batch[mid] < target) lo = mid + 1; else hi = mid; }
        se[tid] = lo;
    }
    __syncthreads();
    int s = se[0], e = se[1];
    const float* plane = (tid < 64) ? cat0 : ((tid < 128) ? cat1 : cat2);
    int col = tid & 63;
    float acc = 0.f;
    for (int r = s; r < e; r++) acc += plane[(size_t)r * 64 + col];
    float denom = (e > s) ? (float)(e - s) : 1.0f;
    p[tid] = acc / denom;
    __syncthreads();
    if (tid < MLP_DIM) {
        float a = fc1b[tid];
        for (int k = 0; k < 192; k++) a = fmaf(p[k], fc1w[k * 128 + tid], a);
        hid[tid] = fmaxf(a, 0.f);
    }
    __syncthreads();
    if (tid < N_CLASSES) {
        float a = fc2b[tid];
        for (int k = 0; k < 128; k++) a = fmaf(hid[k], fc2w[k * 10 + tid], a);
        z[tid] = a;
    }
    __syncthreads();
    if (tid == 0) {
        float m = z[0];
        for (int i = 1; i < 10; i++) m = fmaxf(m, z[i]);
        float sm = 0.f;
        for (int i = 0; i < 10; i++) sm += expf(z[i] - m);
        lse = m + logf(sm);
    }
    __syncthreads();
    if (tid < N_CLASSES) out[g * 10 + tid] = z[tid] - lse;
}

// ============================ launch ============================
extern "C" void kernel_launch(void* const* d_in, const int* in_sizes, int n_in,
                              void* d_out, int out_size, void* d_ws, size_t ws_size,
                              hipStream_t stream) {
    (void)in_sizes; (void)n_in; (void)out_size; (void)ws_size;
    const float* x    = (const float*)d_in[0];
    const int*   ei   = (const int*)d_in[1];
    const int*   batch= (const int*)d_in[2];
    const float* fc0w = (const float*)d_in[3];
    const float* fc0b = (const float*)d_in[4];
    const float* fc1w = (const float*)d_in[5];
    const float* fc1b = (const float*)d_in[6];
    const float* fc2w = (const float*)d_in[7];
    const float* fc2b = (const float*)d_in[8];
    const int* src = ei;
    const int* dst = ei + N_EDGES;
    float* out = (float*)d_out;

    char* w = (char*)d_ws;
    size_t off = 0;
    auto alloc = [&](size_t bytes) -> void* {
        void* p = w + off;
        off = (off + bytes + 255) & ~(size_t)255;
        return p;
    };
    const size_t MAX_PAD_EDGES = (size_t)N_EDGES + 16 * (size_t)N_NODES;

    // zeroed-every-launch block: gcur[NB] | bns[3][NSLICE][128]
    char* zbase = (char*)alloc(1024 + 3 * NSLICE * 128 * 4);
    int*   gcur   = (int*)zbase;                     // NB ints (bucket cursors = final counts)
    float* bnsAll = (float*)(zbase + 1024);          // 3 * NSLICE * 128 floats
    const size_t ZBYTES = 1024 + 3 * NSLICE * 128 * 4;

    float* cat0    = (float*)alloc((size_t)N_NODES * 64 * 4);    // 12.8 MB each plane
    float* cat1    = (float*)alloc((size_t)N_NODES * 64 * 4);
    float* cat2    = (float*)alloc((size_t)N_NODES * 64 * 4);
    float* h0      = (float*)alloc((size_t)N_NODES * 64 * 4);    // 12.8 MB
    float* Ae      = (float*)alloc((size_t)N_NODES * 64 * 4);    // 12.8 MB
    unsigned short* Be = (unsigned short*)alloc((size_t)N_NODES * 64 * 2);  // 6.4 MB (bf16)
    unsigned* keys = (unsigned*)alloc((size_t)NB * CAPB * 4);    // 12.85 MB
    unsigned short* sorted_src = (unsigned short*)alloc(MAX_PAD_EDGES * 2);  // 4.8 MB
    int*   cnt     = (int*)alloc((size_t)N_NODES * 4);
    int*   row_start = (int*)alloc((size_t)(N_NODES + 1) * 4);
    int*   bsum    = (int*)alloc(NB * 4);
    int*   bbase   = (int*)alloc(NB * 4);

    (void)hipMemsetAsync(zbase, 0, ZBYTES, stream);

    // --- two-level counting sort (fixed-capacity buckets): edges -> padded CSR by dst ---
    pass1_kernel<<<(N_EDGES + CHUNK - 1) / CHUNK, 256, 0, stream>>>(src, dst, gcur, keys);
    node_count_kernel<<<NB, 256, 0, stream>>>(keys, gcur, cnt, bsum);
    pscan_kernel<<<1, 256, 0, stream>>>(bsum, bbase, row_start);
    pass2_kernel<<<NB, 256, 0, stream>>>(keys, gcur, cnt, bbase, row_start, sorted_src);

    fc0_kernel<<<1024, 256, 0, stream>>>(x, fc0w, fc0b, h0, bnsAll);

    float* planes[3] = {cat0, cat1, cat2};
    for (int blk = 0; blk < 3; blk++) {
        const float* g  = (const float*)d_in[9 + 6 * blk];
        const float* bb = (const float*)d_in[10 + 6 * blk];
        const float* w1 = (const float*)d_in[11 + 6 * blk];
        const float* b1 = (const float*)d_in[12 + 6 * blk];
        const float* w2 = (const float*)d_in[13 + 6 * blk];
        const float* b2 = (const float*)d_in[14 + 6 * blk];
        const float* hsrc = (blk == 0) ? h0 : planes[blk - 1];

        ab_kernel<<<1024, 256, 0, stream>>>(hsrc, 64, bnsAll + blk * NSLICE * 128,
                                            g, bb, w1, b1, Ae, Be);
        edge_mfma_kernel<<<2048, 256, 0, stream>>>(
            Ae, Be, row_start, sorted_src, w2, b2, planes[blk],
            (blk < 2) ? (bnsAll + (blk + 1) * NSLICE * 128) : nullptr);
    }

    poolhead_kernel<<<N_GRAPHS, 192, 0, stream>>>(cat0, cat1, cat2, batch,
                                                  fc1w, fc1b, fc2w, fc2b, out);
}

// Round 9
// 452.324 us; speedup vs baseline: 2.7560x; 1.0302x over previous
//
#include <hip/hip_runtime.h>
#include <math.h>

#define N_NODES 50000
#define N_EDGES 1600000
#define F_IN 128
#define C 64
#define EF 64
#define N_GRAPHS 512
#define MLP_DIM 128
#define N_CLASSES 10
#define EPS 1e-5f
#define NB 196            // coarse buckets: dst>>8, 256 nodes each
#define CAPB 16384        // fixed bucket capacity (mean 8192, std ~90 -> safe)
#define CHUNK 4096        // edges per pass-1 block
#define NSLICE 8          // bn-stat atomic slices

typedef __attribute__((ext_vector_type(8))) _Float16 half8;
typedef __attribute__((ext_vector_type(2))) _Float16 half2v;
typedef __attribute__((ext_vector_type(4))) float floatx4;
typedef __attribute__((ext_vector_type(4))) unsigned uintx4;

__device__ __forceinline__ unsigned short f2h(float a) {
    union { _Float16 f; unsigned short u; } c;
    c.f = (_Float16)a;   // RNE
    return c.u;
}
__device__ __forceinline__ float h2f(unsigned short u) {
    union { unsigned short u; _Float16 f; } c;
    c.u = u;
    return (float)c.f;
}

// ==================== sort pass 1: bin edges into fixed-capacity buckets ====================
__global__ __launch_bounds__(256) void pass1_kernel(const int* __restrict__ src,
                                                    const int* __restrict__ dst,
                                                    int* __restrict__ gcur,
                                                    unsigned* __restrict__ keys) {
    __shared__ int lcnt[NB], lbase[NB], lcnt2[NB];
    int tid = threadIdx.x;
    int e0 = blockIdx.x * CHUNK;
    unsigned k[CHUNK / 256];
    int bk[CHUNK / 256];
    for (int i = tid; i < NB; i += 256) lcnt[i] = 0;
    __syncthreads();
#pragma unroll
    for (int i = 0; i < CHUNK / 256; i++) {
        int e = e0 + i * 256 + tid;
        if (e < N_EDGES) {
            int d = dst[e];
            k[i] = ((unsigned)d << 16) | (unsigned)src[e];
            bk[i] = d >> 8;
            atomicAdd(&lcnt[bk[i]], 1);
        } else bk[i] = -1;
    }
    __syncthreads();
    for (int i = tid; i < NB; i += 256) {
        int c = lcnt[i];
        lbase[i] = c ? atomicAdd(&gcur[i], c) : 0;
        lcnt2[i] = 0;
    }
    __syncthreads();
#pragma unroll
    for (int i = 0; i < CHUNK / 256; i++) {
        if (bk[i] >= 0) {
            int r = atomicAdd(&lcnt2[bk[i]], 1);
            keys[(size_t)bk[i] * CAPB + lbase[bk[i]] + r] = k[i];
        }
    }
}

// ==================== per-node degree + per-bucket padded sums ====================
__global__ __launch_bounds__(256) void node_count_kernel(const unsigned* __restrict__ keys,
                                                         const int* __restrict__ bcnt,
                                                         int* __restrict__ cnt,
                                                         int* __restrict__ bsum) {
    __shared__ int lc[256], rs[256];
    int tid = threadIdx.x, b = blockIdx.x;
    lc[tid] = 0;
    __syncthreads();
    int beg = b * CAPB, end = beg + bcnt[b];
    for (int p = beg + tid; p < end; p += 256)
        atomicAdd(&lc[(keys[p] >> 16) & 255], 1);
    __syncthreads();
    int node = b * 256 + tid;
    int c = (node < N_NODES) ? lc[tid] : 0;
    if (node < N_NODES) cnt[node] = c;
    rs[tid] = (c + 15) & ~15;
    __syncthreads();
    for (int off = 128; off > 0; off >>= 1) {
        if (tid < off) rs[tid] += rs[tid + off];
        __syncthreads();
    }
    if (tid == 0) bsum[b] = rs[0];
}

// exclusive scan of padded bucket sums -> bbase; writes row_start[N_NODES]
__global__ void pscan_kernel(const int* __restrict__ bsum, int* __restrict__ bbase,
                             int* __restrict__ row_start) {
    __shared__ int a[256];
    int tid = threadIdx.x;
    int v = (tid < NB) ? bsum[tid] : 0;
    a[tid] = v;
    __syncthreads();
    for (int off = 1; off < 256; off <<= 1) {
        int t = (tid >= off) ? a[tid - off] : 0;
        __syncthreads();
        a[tid] += t;
        __syncthreads();
    }
    int excl = a[tid] - v;
    if (tid < NB) bbase[tid] = excl;
    if (tid == NB - 1) row_start[N_NODES] = excl + v;
}

// ==================== pass 2: local scan -> row_start, block-local scatter + pad fill ============
__global__ __launch_bounds__(256) void pass2_kernel(const unsigned* __restrict__ keys,
                                                    const int* __restrict__ bcnt,
                                                    const int* __restrict__ cnt,
                                                    const int* __restrict__ bbase,
                                                    int* __restrict__ row_start,
                                                    unsigned short* __restrict__ sorted_src) {
    __shared__ int loc[256], rs[256], cur[256];
    int tid = threadIdx.x, b = blockIdx.x;
    int node = b * 256 + tid;
    int c = (node < N_NODES) ? cnt[node] : 0;
    int pc = (c + 15) & ~15;
    loc[tid] = pc;
    cur[tid] = 0;
    __syncthreads();
    for (int off = 1; off < 256; off <<= 1) {
        int t = (tid >= off) ? loc[tid - off] : 0;
        __syncthreads();
        loc[tid] += t;
        __syncthreads();
    }
    int myrs = bbase[b] + loc[tid] - pc;  // exclusive
    rs[tid] = myrs;
    if (node < N_NODES) row_start[node] = myrs;
    __syncthreads();
    int beg = b * CAPB, end = beg + bcnt[b];
    for (int p = beg + tid; p < end; p += 256) {
        unsigned k = keys[p];
        int lidx = (k >> 16) & 255;
        int r = atomicAdd(&cur[lidx], 1);
        sorted_src[rs[lidx] + r] = (unsigned short)(k & 0xFFFFu);
    }
    __syncthreads();
    if (node < N_NODES) {
        int deg = cur[tid];
        if (deg > 0) {
            unsigned short s0 = sorted_src[myrs];
            for (int p = myrs + deg; p < myrs + pc; p++) sorted_src[p] = s0;  // max idempotent
        }
    }
}

// ============================ fc0: h0 = x @ fc0_w + fc0_b  (f16 out, + BN stats) ============
__global__ __launch_bounds__(256) void fc0_kernel(const float* __restrict__ x,
                                                  const float* __restrict__ w,
                                                  const float* __restrict__ b,
                                                  unsigned short* __restrict__ h0,
                                                  float* __restrict__ bns) {
    __shared__ float wl[F_IN * C];  // 32 KiB
    __shared__ __align__(16) float xr[4][F_IN];
    __shared__ float r1[4][64], r2[4][64];
    int tid = threadIdx.x, lane = tid & 63, wid = tid >> 6;
    for (int i = tid; i < F_IN * C; i += 256) wl[i] = w[i];
    __syncthreads();
    float bj = b[lane];
    float s1 = 0.f, s2 = 0.f;
    for (int n = blockIdx.x * 4 + wid; n < N_NODES; n += gridDim.x * 4) {
        xr[wid][lane]      = x[n * F_IN + lane];
        xr[wid][64 + lane] = x[n * F_IN + 64 + lane];
        const float4* x4 = (const float4*)xr[wid];
        float a0 = 0, a1 = 0, a2 = 0, a3 = 0;
#pragma unroll
        for (int k4 = 0; k4 < F_IN / 4; k4++) {
            float4 hv = x4[k4];
            a0 = fmaf(hv.x, wl[(4 * k4 + 0) * C + lane], a0);
            a1 = fmaf(hv.y, wl[(4 * k4 + 1) * C + lane], a1);
            a2 = fmaf(hv.z, wl[(4 * k4 + 2) * C + lane], a2);
            a3 = fmaf(hv.w, wl[(4 * k4 + 3) * C + lane], a3);
        }
        float v = (a0 + a1) + (a2 + a3) + bj;
        h0[n * C + lane] = f2h(v);
        s1 += v; s2 += v * v;
    }
    r1[wid][lane] = s1; r2[wid][lane] = s2;
    __syncthreads();
    if (tid < 64) {
        float a  = r1[0][tid] + r1[1][tid] + r1[2][tid] + r1[3][tid];
        float c2 = r2[0][tid] + r2[1][tid] + r2[2][tid] + r2[3][tid];
        int sl = blockIdx.x & (NSLICE - 1);
        atomicAdd(&bns[sl * 128 + tid], a);
        atomicAdd(&bns[sl * 128 + 64 + tid], c2);
    }
}

// ============ ab: fold BN (from bns) + build WA/WB/cAB in LDS, then A/B tables (f16) ============
__global__ __launch_bounds__(256) void ab_kernel(const unsigned short* __restrict__ h,
                                                 const float* __restrict__ bns,
                                                 const float* __restrict__ g,
                                                 const float* __restrict__ bb,
                                                 const float* __restrict__ w1,
                                                 const float* __restrict__ b1,
                                                 unsigned short* __restrict__ A,
                                                 unsigned short* __restrict__ Bb) {
    __shared__ float wal[64 * 64], wbl[64 * 64];  // 32 KiB
    __shared__ float scale[64], shift[64], cab[128];
    __shared__ __align__(16) float hr[4][64];
    int tid = threadIdx.x, lane = tid & 63, wid = tid >> 6;

    // phase 1: BN scale/shift
    if (tid < 64) {
        float s1v = 0.f, s2v = 0.f;
#pragma unroll
        for (int s = 0; s < NSLICE; s++) { s1v += bns[s * 128 + tid]; s2v += bns[s * 128 + 64 + tid]; }
        float mu  = s1v * (1.0f / N_NODES);
        float var = s2v * (1.0f / N_NODES) - mu * mu;
        float sc  = g[tid] * rsqrtf(var + EPS);
        scale[tid] = sc;
        shift[tid] = bb[tid] - mu * sc;
    }
    // phase 2: unscaled diffs into LDS
    for (int i = tid; i < 4096; i += 256) {
        float wbv = w1[(64 + (i >> 6)) * EF + (i & 63)];
        wal[i] = w1[(i >> 6) * EF + (i & 63)] - wbv;
        wbl[i] = wbv;
    }
    __syncthreads();
    // phase 3: cAB from LDS (threads 0..63 -> cA, 64..127 -> cB)
    if (tid < 128) {
        int j = tid & 63;
        const float* m = (tid < 64) ? wal : wbl;
        float acc = (tid < 64) ? b1[j] : 0.f;
        for (int k = 0; k < 64; k++) acc = fmaf(shift[k], m[k * 64 + j], acc);
        cab[tid] = acc;
    }
    __syncthreads();
    // phase 4: apply scale in place
    for (int i = tid; i < 4096; i += 256) {
        float sc = scale[i >> 6];
        wal[i] *= sc;
        wbl[i] *= sc;
    }
    __syncthreads();

    float ca = cab[lane], cb = cab[64 + lane];
    for (int n = blockIdx.x * 4 + wid; n < N_NODES; n += gridDim.x * 4) {
        hr[wid][lane] = h2f(h[(size_t)n * 64 + lane]);
        const float4* h4 = (const float4*)hr[wid];
        float accA = ca, accB = cb;
#pragma unroll
        for (int k4 = 0; k4 < 16; k4++) {
            float4 hv = h4[k4];
            accA = fmaf(hv.x, wal[(4 * k4 + 0) * 64 + lane], accA);
            accB = fmaf(hv.x, wbl[(4 * k4 + 0) * 64 + lane], accB);
            accA = fmaf(hv.y, wal[(4 * k4 + 1) * 64 + lane], accA);
            accB = fmaf(hv.y, wbl[(4 * k4 + 1) * 64 + lane], accB);
            accA = fmaf(hv.z, wal[(4 * k4 + 2) * 64 + lane], accA);
            accB = fmaf(hv.z, wbl[(4 * k4 + 2) * 64 + lane], accB);
            accA = fmaf(hv.w, wal[(4 * k4 + 3) * 64 + lane], accA);
            accB = fmaf(hv.w, wbl[(4 * k4 + 3) * 64 + lane], accB);
        }
        A[n * 64 + lane]  = f2h(accA);
        Bb[n * 64 + lane] = f2h(accB);
    }
}

// ============ EdgeConv via f16 MFMA: f16 A/B tables, pk_f16 add+relu feeds MFMA directly ============
// (256,4): VGPR cap 128, kernel fits ~60 — no spill (R7 lesson: (256,6) spilled, 6x slowdown).
__global__ __launch_bounds__(256, 4) void edge_mfma_kernel(
        const unsigned short* __restrict__ A, const unsigned short* __restrict__ Bb,
        const int* __restrict__ row_start, const unsigned short* __restrict__ sorted_src,
        const float* __restrict__ w2, const float* __restrict__ b2,
        unsigned short* __restrict__ catp, float* __restrict__ bnsNext) {
    __shared__ float r1[4][64], r2[4][64];
    int tid = threadIdx.x, lane = tid & 63, wid = tid >> 6;
    int kq = (lane >> 4) * 8;  // this lane's k-offset within each 32-chunk
    int cl = lane & 15;

    union Uh { uintx4 v; half2v h[4]; half8 h8; };

    // w2 fragments (f16), wave-invariant, in registers
    Uh bfr[2][4];
#pragma unroll
    for (int kh = 0; kh < 2; kh++)
#pragma unroll
        for (int cb = 0; cb < 4; cb++)
#pragma unroll
            for (int j = 0; j < 4; j++) {
                _Float16 w0 = (_Float16)w2[(kh * 32 + kq + 2 * j) * 64 + cb * 16 + cl];
                _Float16 w1 = (_Float16)w2[(kh * 32 + kq + 2 * j + 1) * 64 + cb * 16 + cl];
                bfr[kh][cb].h[j] = half2v{w0, w1};
            }
    float b2j = b2[lane];
    float s1 = 0.f, s2 = 0.f;
    const half2v zeroh = {(_Float16)0.f, (_Float16)0.f};

    for (int n = blockIdx.x * 4 + wid; n < N_NODES; n += gridDim.x * 4) {
        int beg = row_start[n], end = row_start[n + 1];
        const unsigned short* arow = A + (size_t)n * 64 + kq;
        Uh a0u, a1u;
        a0u.v = *(const uintx4*)(arow);        // f16 x8: k = kq..kq+7
        a1u.v = *(const uintx4*)(arow + 32);   // f16 x8: k = 32+kq..
        floatx4 rmax0 = {-INFINITY, -INFINITY, -INFINITY, -INFINITY};
        floatx4 rmax1 = rmax0, rmax2 = rmax0, rmax3 = rmax0;

        auto tile = [&](uintx4 u0, uintx4 u1) {
            Uh b0u, b1u, f0, f1;
            b0u.v = u0; b1u.v = u1;
#pragma unroll
            for (int j = 0; j < 4; j++) {      // v_pk_add_f16 + v_pk_max_f16
                f0.h[j] = __builtin_elementwise_max(a0u.h[j] + b0u.h[j], zeroh);
                f1.h[j] = __builtin_elementwise_max(a1u.h[j] + b1u.h[j], zeroh);
            }
            floatx4 acc0 = {0.f, 0.f, 0.f, 0.f}, acc1 = acc0, acc2 = acc0, acc3 = acc0;
            acc0 = __builtin_amdgcn_mfma_f32_16x16x32_f16(f0.h8, bfr[0][0].h8, acc0, 0, 0, 0);
            acc1 = __builtin_amdgcn_mfma_f32_16x16x32_f16(f0.h8, bfr[0][1].h8, acc1, 0, 0, 0);
            acc2 = __builtin_amdgcn_mfma_f32_16x16x32_f16(f0.h8, bfr[0][2].h8, acc2, 0, 0, 0);
            acc3 = __builtin_amdgcn_mfma_f32_16x16x32_f16(f0.h8, bfr[0][3].h8, acc3, 0, 0, 0);
            acc0 = __builtin_amdgcn_mfma_f32_16x16x32_f16(f1.h8, bfr[1][0].h8, acc0, 0, 0, 0);
            acc1 = __builtin_amdgcn_mfma_f32_16x16x32_f16(f1.h8, bfr[1][1].h8, acc1, 0, 0, 0);
            acc2 = __builtin_amdgcn_mfma_f32_16x16x32_f16(f1.h8, bfr[1][2].h8, acc2, 0, 0, 0);
            acc3 = __builtin_amdgcn_mfma_f32_16x16x32_f16(f1.h8, bfr[1][3].h8, acc3, 0, 0, 0);
            rmax0 = __builtin_elementwise_max(rmax0, acc0);
            rmax1 = __builtin_elementwise_max(rmax1, acc1);
            rmax2 = __builtin_elementwise_max(rmax2, acc2);
            rmax3 = __builtin_elementwise_max(rmax3, acc3);
        };
        auto gather = [&](int p, uintx4& u0, uintx4& u1) {
            int srcm = sorted_src[p + cl];
            const unsigned short* brow = Bb + (size_t)srcm * 64 + kq;
            u0 = *(const uintx4*)(brow);
            u1 = *(const uintx4*)(brow + 32);
        };

        int p0 = beg;
        for (; p0 + 32 <= end; p0 += 32) {   // two tiles per iter: both gathers in flight
            uintx4 x0, x1, y0, y1;
            gather(p0, x0, x1);
            gather(p0 + 16, y0, y1);
            tile(x0, x1);
            tile(y0, y1);
        }
        if (p0 < end) {                       // odd-tile remainder
            uintx4 x0, x1;
            gather(p0, x0, x1);
            tile(x0, x1);
        }

        float v0 = fmaxf(fmaxf(rmax0.x, rmax0.y), fmaxf(rmax0.z, rmax0.w));
        float v1 = fmaxf(fmaxf(rmax1.x, rmax1.y), fmaxf(rmax1.z, rmax1.w));
        float v2 = fmaxf(fmaxf(rmax2.x, rmax2.y), fmaxf(rmax2.z, rmax2.w));
        float v3 = fmaxf(fmaxf(rmax3.x, rmax3.y), fmaxf(rmax3.z, rmax3.w));
        v0 = fmaxf(v0, __shfl_xor(v0, 16)); v0 = fmaxf(v0, __shfl_xor(v0, 32));
        v1 = fmaxf(v1, __shfl_xor(v1, 16)); v1 = fmaxf(v1, __shfl_xor(v1, 32));
        v2 = fmaxf(v2, __shfl_xor(v2, 16)); v2 = fmaxf(v2, __shfl_xor(v2, 32));
        v3 = fmaxf(v3, __shfl_xor(v3, 16)); v3 = fmaxf(v3, __shfl_xor(v3, 32));
        float vs = (lane & 32) ? ((lane & 16) ? v3 : v2) : ((lane & 16) ? v1 : v0);
        float v = fmaxf(vs + b2j, 0.f);  // -inf (empty node) -> 0; folds where(isfinite)+relu
        catp[(size_t)n * 64 + lane] = f2h(v);
        s1 += v; s2 += v * v;
    }

    if (bnsNext) {
        r1[wid][lane] = s1; r2[wid][lane] = s2;
        __syncthreads();
        if (tid < 64) {
            float a  = r1[0][tid] + r1[1][tid] + r1[2][tid] + r1[3][tid];
            float c2 = r2[0][tid] + r2[1][tid] + r2[2][tid] + r2[3][tid];
            int sl = blockIdx.x & (NSLICE - 1);
            atomicAdd(&bnsNext[sl * 128 + tid], a);
            atomicAdd(&bnsNext[sl * 128 + 64 + tid], c2);
        }
    }
}

// ============================ fused graph mean pool + MLP head + log_softmax ============================
__global__ __launch_bounds__(192) void poolhead_kernel(const unsigned short* __restrict__ cat0,
                                                       const unsigned short* __restrict__ cat1,
                                                       const unsigned short* __restrict__ cat2,
                                                       const int* __restrict__ batch,
                                                       const float* __restrict__ fc1w,
                                                       const float* __restrict__ fc1b,
                                                       const float* __restrict__ fc2w,
                                                       const float* __restrict__ fc2b,
                                                       float* __restrict__ out) {
    __shared__ int se[2];
    __shared__ float p[192];
    __shared__ float hid[128];
    __shared__ float z[10];
    __shared__ float lse;
    int g = blockIdx.x, tid = threadIdx.x;  // 192 threads
    if (tid < 2) {
        int target = g + tid;
        int lo = 0, hi = N_NODES;
        while (lo < hi) { int mid = (lo + hi) >> 1; if (batch[mid] < target) lo = mid + 1; else hi = mid; }
        se[tid] = lo;
    }
    __syncthreads();
    int s = se[0], e = se[1];
    const unsigned short* plane = (tid < 64) ? cat0 : ((tid < 128) ? cat1 : cat2);
    int col = tid & 63;
    float acc = 0.f;
    for (int r = s; r < e; r++) acc += h2f(plane[(size_t)r * 64 + col]);
    float denom = (e > s) ? (float)(e - s) : 1.0f;
    p[tid] = acc / denom;
    __syncthreads();
    if (tid < MLP_DIM) {
        float a = fc1b[tid];
        for (int k = 0; k < 192; k++) a = fmaf(p[k], fc1w[k * 128 + tid], a);
        hid[tid] = fmaxf(a, 0.f);
    }
    __syncthreads();
    if (tid < N_CLASSES) {
        float a = fc2b[tid];
        for (int k = 0; k < 128; k++) a = fmaf(hid[k], fc2w[k * 10 + tid], a);
        z[tid] = a;
    }
    __syncthreads();
    if (tid == 0) {
        float m = z[0];
        for (int i = 1; i < 10; i++) m = fmaxf(m, z[i]);
        float sm = 0.f;
        for (int i = 0; i < 10; i++) sm += expf(z[i] - m);
        lse = m + logf(sm);
    }
    __syncthreads();
    if (tid < N_CLASSES) out[g * 10 + tid] = z[tid] - lse;
}

// ============================ launch ============================
extern "C" void kernel_launch(void* const* d_in, const int* in_sizes, int n_in,
                              void* d_out, int out_size, void* d_ws, size_t ws_size,
                              hipStream_t stream) {
    (void)in_sizes; (void)n_in; (void)out_size; (void)ws_size;
    const float* x    = (const float*)d_in[0];
    const int*   ei   = (const int*)d_in[1];
    const int*   batch= (const int*)d_in[2];
    const float* fc0w = (const float*)d_in[3];
    const float* fc0b = (const float*)d_in[4];
    const float* fc1w = (const float*)d_in[5];
    const float* fc1b = (const float*)d_in[6];
    const float* fc2w = (const float*)d_in[7];
    const float* fc2b = (const float*)d_in[8];
    const int* src = ei;
    const int* dst = ei + N_EDGES;
    float* out = (float*)d_out;

    char* w = (char*)d_ws;
    size_t off = 0;
    auto alloc = [&](size_t bytes) -> void* {
        void* p = w + off;
        off = (off + bytes + 255) & ~(size_t)255;
        return p;
    };
    const size_t MAX_PAD_EDGES = (size_t)N_EDGES + 16 * (size_t)N_NODES;

    // zeroed-every-launch block: gcur[NB] | bns[3][NSLICE][128]
    char* zbase = (char*)alloc(1024 + 3 * NSLICE * 128 * 4);
    int*   gcur   = (int*)zbase;                     // NB ints (bucket cursors = final counts)
    float* bnsAll = (float*)(zbase + 1024);          // 3 * NSLICE * 128 floats
    const size_t ZBYTES = 1024 + 3 * NSLICE * 128 * 4;

    unsigned short* cat0 = (unsigned short*)alloc((size_t)N_NODES * 64 * 2);  // 6.4 MB/plane (f16)
    unsigned short* cat1 = (unsigned short*)alloc((size_t)N_NODES * 64 * 2);
    unsigned short* cat2 = (unsigned short*)alloc((size_t)N_NODES * 64 * 2);
    unsigned short* h0   = (unsigned short*)alloc((size_t)N_NODES * 64 * 2);  // 6.4 MB (f16)
    unsigned short* Ae   = (unsigned short*)alloc((size_t)N_NODES * 64 * 2);  // 6.4 MB (f16)
    unsigned short* Be   = (unsigned short*)alloc((size_t)N_NODES * 64 * 2);  // 6.4 MB (f16)
    unsigned* keys = (unsigned*)alloc((size_t)NB * CAPB * 4);    // 12.85 MB
    unsigned short* sorted_src = (unsigned short*)alloc(MAX_PAD_EDGES * 2);  // 4.8 MB
    int*   cnt     = (int*)alloc((size_t)N_NODES * 4);
    int*   row_start = (int*)alloc((size_t)(N_NODES + 1) * 4);
    int*   bsum    = (int*)alloc(NB * 4);
    int*   bbase   = (int*)alloc(NB * 4);

    (void)hipMemsetAsync(zbase, 0, ZBYTES, stream);

    // --- two-level counting sort (fixed-capacity buckets): edges -> padded CSR by dst ---
    pass1_kernel<<<(N_EDGES + CHUNK - 1) / CHUNK, 256, 0, stream>>>(src, dst, gcur, keys);
    node_count_kernel<<<NB, 256, 0, stream>>>(keys, gcur, cnt, bsum);
    pscan_kernel<<<1, 256, 0, stream>>>(bsum, bbase, row_start);
    pass2_kernel<<<NB, 256, 0, stream>>>(keys, gcur, cnt, bbase, row_start, sorted_src);

    fc0_kernel<<<1024, 256, 0, stream>>>(x, fc0w, fc0b, h0, bnsAll);

    unsigned short* planes[3] = {cat0, cat1, cat2};
    for (int blk = 0; blk < 3; blk++) {
        const float* g  = (const float*)d_in[9 + 6 * blk];
        const float* bb = (const float*)d_in[10 + 6 * blk];
        const float* w1 = (const float*)d_in[11 + 6 * blk];
        const float* b1 = (const float*)d_in[12 + 6 * blk];
        const float* w2 = (const float*)d_in[13 + 6 * blk];
        const float* b2 = (const float*)d_in[14 + 6 * blk];
        const unsigned short* hsrc = (blk == 0) ? h0 : planes[blk - 1];

        ab_kernel<<<1024, 256, 0, stream>>>(hsrc, bnsAll + blk * NSLICE * 128,
                                            g, bb, w1, b1, Ae, Be);
        edge_mfma_kernel<<<2048, 256, 0, stream>>>(
            Ae, Be, row_start, sorted_src, w2, b2, planes[blk],
            (blk < 2) ? (bnsAll + (blk + 1) * NSLICE * 128) : nullptr);
    }

    poolhead_kernel<<<N_GRAPHS, 192, 0, stream>>>(cat0, cat1, cat2, batch,
                                                  fc1w, fc1b, fc2w, fc2b, out);
}

// Round 10
// 428.530 us; speedup vs baseline: 2.9090x; 1.0555x over previous
//
#include <hip/hip_runtime.h>
#include <math.h>

#define N_NODES 50000
#define N_TILES 3125      // N_NODES / 16 exactly
#define N_EDGES 1600000
#define F_IN 128
#define C 64
#define EF 64
#define N_GRAPHS 512
#define MLP_DIM 128
#define N_CLASSES 10
#define EPS 1e-5f
#define NB 196            // coarse buckets: dst>>8, 256 nodes each
#define CAPB 16384        // fixed bucket capacity (mean 8192, std ~90 -> safe)
#define CHUNK 4096        // edges per pass-1 block
#define NSLICE 8          // bn-stat atomic slices

typedef __attribute__((ext_vector_type(8))) _Float16 half8;
typedef __attribute__((ext_vector_type(2))) _Float16 half2v;
typedef __attribute__((ext_vector_type(4))) float floatx4;
typedef __attribute__((ext_vector_type(4))) unsigned uintx4;

union Uh { uintx4 v; half2v h[4]; half8 h8; };

__device__ __forceinline__ unsigned short f2h(float a) {
    union { _Float16 f; unsigned short u; } c;
    c.f = (_Float16)a;   // RNE
    return c.u;
}
__device__ __forceinline__ float h2f(unsigned short u) {
    union { unsigned short u; _Float16 f; } c;
    c.u = u;
    return (float)c.f;
}
__device__ __forceinline__ half2v pk2(float a, float b) {
    auto t = __builtin_amdgcn_cvt_pkrtz(a, b);   // __fp16 vec2 -> bit-cast (R6 lesson)
    union { decltype(t) i; half2v o; } c;
    c.i = t;
    return c.o;
}

// ==================== sort pass 1: bin edges into fixed-capacity buckets ====================
__global__ __launch_bounds__(256) void pass1_kernel(const int* __restrict__ src,
                                                    const int* __restrict__ dst,
                                                    int* __restrict__ gcur,
                                                    unsigned* __restrict__ keys) {
    __shared__ int lcnt[NB], lbase[NB], lcnt2[NB];
    int tid = threadIdx.x;
    int e0 = blockIdx.x * CHUNK;
    unsigned k[CHUNK / 256];
    int bk[CHUNK / 256];
    for (int i = tid; i < NB; i += 256) lcnt[i] = 0;
    __syncthreads();
#pragma unroll
    for (int i = 0; i < CHUNK / 256; i++) {
        int e = e0 + i * 256 + tid;
        if (e < N_EDGES) {
            int d = dst[e];
            k[i] = ((unsigned)d << 16) | (unsigned)src[e];
            bk[i] = d >> 8;
            atomicAdd(&lcnt[bk[i]], 1);
        } else bk[i] = -1;
    }
    __syncthreads();
    for (int i = tid; i < NB; i += 256) {
        int c = lcnt[i];
        lbase[i] = c ? atomicAdd(&gcur[i], c) : 0;
        lcnt2[i] = 0;
    }
    __syncthreads();
#pragma unroll
    for (int i = 0; i < CHUNK / 256; i++) {
        if (bk[i] >= 0) {
            int r = atomicAdd(&lcnt2[bk[i]], 1);
            keys[(size_t)bk[i] * CAPB + lbase[bk[i]] + r] = k[i];
        }
    }
}

// ==================== per-node degree + per-bucket padded sums ====================
__global__ __launch_bounds__(256) void node_count_kernel(const unsigned* __restrict__ keys,
                                                         const int* __restrict__ bcnt,
                                                         int* __restrict__ cnt,
                                                         int* __restrict__ bsum) {
    __shared__ int lc[256], rs[256];
    int tid = threadIdx.x, b = blockIdx.x;
    lc[tid] = 0;
    __syncthreads();
    int beg = b * CAPB, end = beg + bcnt[b];
    for (int p = beg + tid; p < end; p += 256)
        atomicAdd(&lc[(keys[p] >> 16) & 255], 1);
    __syncthreads();
    int node = b * 256 + tid;
    int c = (node < N_NODES) ? lc[tid] : 0;
    if (node < N_NODES) cnt[node] = c;
    rs[tid] = (c + 15) & ~15;
    __syncthreads();
    for (int off = 128; off > 0; off >>= 1) {
        if (tid < off) rs[tid] += rs[tid + off];
        __syncthreads();
    }
    if (tid == 0) bsum[b] = rs[0];
}

// exclusive scan of padded bucket sums -> bbase; writes row_start[N_NODES]
__global__ void pscan_kernel(const int* __restrict__ bsum, int* __restrict__ bbase,
                             int* __restrict__ row_start) {
    __shared__ int a[256];
    int tid = threadIdx.x;
    int v = (tid < NB) ? bsum[tid] : 0;
    a[tid] = v;
    __syncthreads();
    for (int off = 1; off < 256; off <<= 1) {
        int t = (tid >= off) ? a[tid - off] : 0;
        __syncthreads();
        a[tid] += t;
        __syncthreads();
    }
    int excl = a[tid] - v;
    if (tid < NB) bbase[tid] = excl;
    if (tid == NB - 1) row_start[N_NODES] = excl + v;
}

// ==================== pass 2: local scan -> row_start, block-local scatter + pad fill ============
__global__ __launch_bounds__(256) void pass2_kernel(const unsigned* __restrict__ keys,
                                                    const int* __restrict__ bcnt,
                                                    const int* __restrict__ cnt,
                                                    const int* __restrict__ bbase,
                                                    int* __restrict__ row_start,
                                                    unsigned short* __restrict__ sorted_src) {
    __shared__ int loc[256], rs[256], cur[256];
    int tid = threadIdx.x, b = blockIdx.x;
    int node = b * 256 + tid;
    int c = (node < N_NODES) ? cnt[node] : 0;
    int pc = (c + 15) & ~15;
    loc[tid] = pc;
    cur[tid] = 0;
    __syncthreads();
    for (int off = 1; off < 256; off <<= 1) {
        int t = (tid >= off) ? loc[tid - off] : 0;
        __syncthreads();
        loc[tid] += t;
        __syncthreads();
    }
    int myrs = bbase[b] + loc[tid] - pc;  // exclusive
    rs[tid] = myrs;
    if (node < N_NODES) row_start[node] = myrs;
    __syncthreads();
    int beg = b * CAPB, end = beg + bcnt[b];
    for (int p = beg + tid; p < end; p += 256) {
        unsigned k = keys[p];
        int lidx = (k >> 16) & 255;
        int r = atomicAdd(&cur[lidx], 1);
        sorted_src[rs[lidx] + r] = (unsigned short)(k & 0xFFFFu);
    }
    __syncthreads();
    if (node < N_NODES) {
        int deg = cur[tid];
        if (deg > 0) {
            unsigned short s0 = sorted_src[myrs];
            for (int p = myrs + deg; p < myrs + pc; p++) sorted_src[p] = s0;  // max idempotent
        }
    }
}

// ============ fc0 via MFMA: h0[16-node tile] = x @ fc0_w + b (f16 out) + BN stats ============
// M=16 nodes, K=128 (4 chunks), N=64 (4 col-blocks). W frags = 64 VGPRs -> (256,3) cap 170.
__global__ __launch_bounds__(256, 3) void fc0_mfma_kernel(const float* __restrict__ x,
                                                          const float* __restrict__ w,
                                                          const float* __restrict__ b,
                                                          unsigned short* __restrict__ h0,
                                                          float* __restrict__ bns) {
    __shared__ float bl1[4][64], bl2[4][64];
    int tid = threadIdx.x, lane = tid & 63, wid = tid >> 6;
    int q = lane >> 4, cl = lane & 15, kq = q * 8;

    Uh wf[4][4];
#pragma unroll
    for (int kh = 0; kh < 4; kh++)
#pragma unroll
        for (int cb = 0; cb < 4; cb++)
#pragma unroll
            for (int j = 0; j < 4; j++) {
                int k0 = kh * 32 + kq + 2 * j;
                int col = cb * 16 + cl;
                wf[kh][cb].h[j] = pk2(w[k0 * 64 + col], w[(k0 + 1) * 64 + col]);
            }
    float bv[4];
#pragma unroll
    for (int cb = 0; cb < 4; cb++) bv[cb] = b[cb * 16 + cl];
    float s1[4] = {0, 0, 0, 0}, s2[4] = {0, 0, 0, 0};

    for (int t = blockIdx.x * 4 + wid; t < N_TILES; t += gridDim.x * 4) {
        int nb = t * 16;
        floatx4 acc[4] = {{0,0,0,0},{0,0,0,0},{0,0,0,0},{0,0,0,0}};
#pragma unroll
        for (int kh = 0; kh < 4; kh++) {
            const float* xr = x + (size_t)(nb + cl) * F_IN + kh * 32 + kq;
            floatx4 xa = *(const floatx4*)xr;
            floatx4 xb = *(const floatx4*)(xr + 4);
            Uh xf;
            xf.h[0] = pk2(xa.x, xa.y); xf.h[1] = pk2(xa.z, xa.w);
            xf.h[2] = pk2(xb.x, xb.y); xf.h[3] = pk2(xb.z, xb.w);
#pragma unroll
            for (int cb = 0; cb < 4; cb++)
                acc[cb] = __builtin_amdgcn_mfma_f32_16x16x32_f16(xf.h8, wf[kh][cb].h8, acc[cb], 0, 0, 0);
        }
#pragma unroll
        for (int cb = 0; cb < 4; cb++)
#pragma unroll
            for (int r = 0; r < 4; r++) {
                float v = acc[cb][r] + bv[cb];            // node = nb+q*4+r, col = cb*16+cl
                h0[(size_t)(nb + q * 4 + r) * 64 + cb * 16 + cl] = f2h(v);
                s1[cb] += v; s2[cb] += v * v;
            }
    }
    // reduce BN stats: quads hold same cols -> xor-shuffle, then block LDS, sliced atomics
#pragma unroll
    for (int cb = 0; cb < 4; cb++) {
        s1[cb] += __shfl_xor(s1[cb], 16); s1[cb] += __shfl_xor(s1[cb], 32);
        s2[cb] += __shfl_xor(s2[cb], 16); s2[cb] += __shfl_xor(s2[cb], 32);
    }
    if (lane < 16) {
#pragma unroll
        for (int cb = 0; cb < 4; cb++) { bl1[wid][cb * 16 + lane] = s1[cb]; bl2[wid][cb * 16 + lane] = s2[cb]; }
    }
    __syncthreads();
    if (tid < 64) {
        float a  = bl1[0][tid] + bl1[1][tid] + bl1[2][tid] + bl1[3][tid];
        float c2 = bl2[0][tid] + bl2[1][tid] + bl2[2][tid] + bl2[3][tid];
        int sl = blockIdx.x & (NSLICE - 1);
        atomicAdd(&bns[sl * 128 + tid], a);
        atomicAdd(&bns[sl * 128 + 64 + tid], c2);
    }
}

// ============ ab via MFMA: A = bn(h)@WA + cA, B = bn(h)@WB + cB (both f16) ============
// BN folded into W frags (scale) and cA/cB (shift). h is f16 in A-operand layout already.
__global__ __launch_bounds__(256, 4) void ab_mfma_kernel(const unsigned short* __restrict__ h,
                                                         const float* __restrict__ bns,
                                                         const float* __restrict__ g,
                                                         const float* __restrict__ bb,
                                                         const float* __restrict__ w1,
                                                         const float* __restrict__ b1,
                                                         unsigned short* __restrict__ A,
                                                         unsigned short* __restrict__ Bb) {
    __shared__ float scale[64], shift[64], cab[128];
    int tid = threadIdx.x, lane = tid & 63, wid = tid >> 6;
    int q = lane >> 4, cl = lane & 15, kq = q * 8;

    if (tid < 64) {
        float s1v = 0.f, s2v = 0.f;
#pragma unroll
        for (int s = 0; s < NSLICE; s++) { s1v += bns[s * 128 + tid]; s2v += bns[s * 128 + 64 + tid]; }
        float mu  = s1v * (1.0f / N_NODES);
        float var = s2v * (1.0f / N_NODES) - mu * mu;
        float sc  = g[tid] * rsqrtf(var + EPS);
        scale[tid] = sc;
        shift[tid] = bb[tid] - mu * sc;
    }
    __syncthreads();
    // cA/cB (threads 0..63 -> cA, 64..127 -> cB), straight from global w1 (L2-hot)
    if (tid < 128) {
        int j = tid & 63;
        float acc = (tid < 64) ? b1[j] : 0.f;
        for (int k = 0; k < 64; k++) {
            float wa_ = w1[k * EF + j], wb_ = w1[(64 + k) * EF + j];
            acc = fmaf(shift[k], (tid < 64) ? (wa_ - wb_) : wb_, acc);
        }
        cab[tid] = acc;
    }
    // W fragments with scale folded (32 VGPRs)
    Uh wa[2][4], wb[2][4];
#pragma unroll
    for (int kh = 0; kh < 2; kh++)
#pragma unroll
        for (int cb = 0; cb < 4; cb++)
#pragma unroll
            for (int j = 0; j < 4; j++) {
                int k0 = kh * 32 + kq + 2 * j;
                int col = cb * 16 + cl;
                float sa = scale[k0], sb = scale[k0 + 1];
                float a0 = w1[k0 * EF + col], b0 = w1[(64 + k0) * EF + col];
                float a1 = w1[(k0 + 1) * EF + col], b1v = w1[(64 + k0 + 1) * EF + col];
                wa[kh][cb].h[j] = pk2(sa * (a0 - b0), sb * (a1 - b1v));
                wb[kh][cb].h[j] = pk2(sa * b0, sb * b1v);
            }
    __syncthreads();
    float cav[4], cbv[4];
#pragma unroll
    for (int cb = 0; cb < 4; cb++) { cav[cb] = cab[cb * 16 + cl]; cbv[cb] = cab[64 + cb * 16 + cl]; }

    for (int t = blockIdx.x * 4 + wid; t < N_TILES; t += gridDim.x * 4) {
        int nb = t * 16;
        const unsigned short* hrow = h + (size_t)(nb + cl) * 64 + kq;
        Uh h0f, h1f;
        h0f.v = *(const uintx4*)hrow;
        h1f.v = *(const uintx4*)(hrow + 32);
        floatx4 accA[4] = {{0,0,0,0},{0,0,0,0},{0,0,0,0},{0,0,0,0}};
        floatx4 accB[4] = {{0,0,0,0},{0,0,0,0},{0,0,0,0},{0,0,0,0}};
#pragma unroll
        for (int cb = 0; cb < 4; cb++) {
            accA[cb] = __builtin_amdgcn_mfma_f32_16x16x32_f16(h0f.h8, wa[0][cb].h8, accA[cb], 0, 0, 0);
            accB[cb] = __builtin_amdgcn_mfma_f32_16x16x32_f16(h0f.h8, wb[0][cb].h8, accB[cb], 0, 0, 0);
            accA[cb] = __builtin_amdgcn_mfma_f32_16x16x32_f16(h1f.h8, wa[1][cb].h8, accA[cb], 0, 0, 0);
            accB[cb] = __builtin_amdgcn_mfma_f32_16x16x32_f16(h1f.h8, wb[1][cb].h8, accB[cb], 0, 0, 0);
        }
#pragma unroll
        for (int cb = 0; cb < 4; cb++)
#pragma unroll
            for (int r = 0; r < 4; r++) {
                size_t o = (size_t)(nb + q * 4 + r) * 64 + cb * 16 + cl;
                A[o]  = f2h(accA[cb][r] + cav[cb]);
                Bb[o] = f2h(accB[cb][r] + cbv[cb]);
            }
    }
}

// ============ EdgeConv via f16 MFMA: f16 A/B tables, pk_f16 add+relu feeds MFMA directly ============
// (256,4): VGPR cap 128, kernel fits ~64 — no spill (R7 lesson: (256,6) spilled, 6x slowdown).
__global__ __launch_bounds__(256, 4) void edge_mfma_kernel(
        const unsigned short* __restrict__ A, const unsigned short* __restrict__ Bb,
        const int* __restrict__ row_start, const unsigned short* __restrict__ sorted_src,
        const float* __restrict__ w2, const float* __restrict__ b2,
        unsigned short* __restrict__ catp, float* __restrict__ bnsNext) {
    __shared__ float r1[4][64], r2[4][64];
    int tid = threadIdx.x, lane = tid & 63, wid = tid >> 6;
    int kq = (lane >> 4) * 8;  // this lane's k-offset within each 32-chunk
    int cl = lane & 15;

    // w2 fragments (f16), wave-invariant, in registers
    Uh bfr[2][4];
#pragma unroll
    for (int kh = 0; kh < 2; kh++)
#pragma unroll
        for (int cb = 0; cb < 4; cb++)
#pragma unroll
            for (int j = 0; j < 4; j++) {
                _Float16 w0 = (_Float16)w2[(kh * 32 + kq + 2 * j) * 64 + cb * 16 + cl];
                _Float16 w1 = (_Float16)w2[(kh * 32 + kq + 2 * j + 1) * 64 + cb * 16 + cl];
                bfr[kh][cb].h[j] = half2v{w0, w1};
            }
    float b2j = b2[lane];
    float s1 = 0.f, s2 = 0.f;
    const half2v zeroh = {(_Float16)0.f, (_Float16)0.f};

    for (int n = blockIdx.x * 4 + wid; n < N_NODES; n += gridDim.x * 4) {
        int beg = row_start[n], end = row_start[n + 1];
        const unsigned short* arow = A + (size_t)n * 64 + kq;
        Uh a0u, a1u;
        a0u.v = *(const uintx4*)(arow);        // f16 x8: k = kq..kq+7
        a1u.v = *(const uintx4*)(arow + 32);   // f16 x8: k = 32+kq..
        floatx4 rmax0 = {-INFINITY, -INFINITY, -INFINITY, -INFINITY};
        floatx4 rmax1 = rmax0, rmax2 = rmax0, rmax3 = rmax0;

        auto tile = [&](uintx4 u0, uintx4 u1) {
            Uh b0u, b1u, f0, f1;
            b0u.v = u0; b1u.v = u1;
#pragma unroll
            for (int j = 0; j < 4; j++) {      // v_pk_add_f16 + v_pk_max_f16
                f0.h[j] = __builtin_elementwise_max(a0u.h[j] + b0u.h[j], zeroh);
                f1.h[j] = __builtin_elementwise_max(a1u.h[j] + b1u.h[j], zeroh);
            }
            floatx4 acc0 = {0.f, 0.f, 0.f, 0.f}, acc1 = acc0, acc2 = acc0, acc3 = acc0;
            acc0 = __builtin_amdgcn_mfma_f32_16x16x32_f16(f0.h8, bfr[0][0].h8, acc0, 0, 0, 0);
            acc1 = __builtin_amdgcn_mfma_f32_16x16x32_f16(f0.h8, bfr[0][1].h8, acc1, 0, 0, 0);
            acc2 = __builtin_amdgcn_mfma_f32_16x16x32_f16(f0.h8, bfr[0][2].h8, acc2, 0, 0, 0);
            acc3 = __builtin_amdgcn_mfma_f32_16x16x32_f16(f0.h8, bfr[0][3].h8, acc3, 0, 0, 0);
            acc0 = __builtin_amdgcn_mfma_f32_16x16x32_f16(f1.h8, bfr[1][0].h8, acc0, 0, 0, 0);
            acc1 = __builtin_amdgcn_mfma_f32_16x16x32_f16(f1.h8, bfr[1][1].h8, acc1, 0, 0, 0);
            acc2 = __builtin_amdgcn_mfma_f32_16x16x32_f16(f1.h8, bfr[1][2].h8, acc2, 0, 0, 0);
            acc3 = __builtin_amdgcn_mfma_f32_16x16x32_f16(f1.h8, bfr[1][3].h8, acc3, 0, 0, 0);
            rmax0 = __builtin_elementwise_max(rmax0, acc0);
            rmax1 = __builtin_elementwise_max(rmax1, acc1);
            rmax2 = __builtin_elementwise_max(rmax2, acc2);
            rmax3 = __builtin_elementwise_max(rmax3, acc3);
        };
        auto gather = [&](int p, uintx4& u0, uintx4& u1) {
            int srcm = sorted_src[p + cl];
            const unsigned short* brow = Bb + (size_t)srcm * 64 + kq;
            u0 = *(const uintx4*)(brow);
            u1 = *(const uintx4*)(brow + 32);
        };

        int p0 = beg;
        for (; p0 + 32 <= end; p0 += 32) {   // two tiles per iter: both gathers in flight
            uintx4 x0, x1, y0, y1;
            gather(p0, x0, x1);
            gather(p0 + 16, y0, y1);
            tile(x0, x1);
            tile(y0, y1);
        }
        if (p0 < end) {                       // odd-tile remainder
            uintx4 x0, x1;
            gather(p0, x0, x1);
            tile(x0, x1);
        }

        float v0 = fmaxf(fmaxf(rmax0.x, rmax0.y), fmaxf(rmax0.z, rmax0.w));
        float v1 = fmaxf(fmaxf(rmax1.x, rmax1.y), fmaxf(rmax1.z, rmax1.w));
        float v2 = fmaxf(fmaxf(rmax2.x, rmax2.y), fmaxf(rmax2.z, rmax2.w));
        float v3 = fmaxf(fmaxf(rmax3.x, rmax3.y), fmaxf(rmax3.z, rmax3.w));
        v0 = fmaxf(v0, __shfl_xor(v0, 16)); v0 = fmaxf(v0, __shfl_xor(v0, 32));
        v1 = fmaxf(v1, __shfl_xor(v1, 16)); v1 = fmaxf(v1, __shfl_xor(v1, 32));
        v2 = fmaxf(v2, __shfl_xor(v2, 16)); v2 = fmaxf(v2, __shfl_xor(v2, 32));
        v3 = fmaxf(v3, __shfl_xor(v3, 16)); v3 = fmaxf(v3, __shfl_xor(v3, 32));
        float vs = (lane & 32) ? ((lane & 16) ? v3 : v2) : ((lane & 16) ? v1 : v0);
        float v = fmaxf(vs + b2j, 0.f);  // -inf (empty node) -> 0; folds where(isfinite)+relu
        catp[(size_t)n * 64 + lane] = f2h(v);
        s1 += v; s2 += v * v;
    }

    if (bnsNext) {
        r1[wid][lane] = s1; r2[wid][lane] = s2;
        __syncthreads();
        if (tid < 64) {
            float a  = r1[0][tid] + r1[1][tid] + r1[2][tid] + r1[3][tid];
            float c2 = r2[0][tid] + r2[1][tid] + r2[2][tid] + r2[3][tid];
            int sl = blockIdx.x & (NSLICE - 1);
            atomicAdd(&bnsNext[sl * 128 + tid], a);
            atomicAdd(&bnsNext[sl * 128 + 64 + tid], c2);
        }
    }
}

// ============================ fused graph mean pool + MLP head + log_softmax ============================
__global__ __launch_bounds__(192) void poolhead_kernel(const unsigned short* __restrict__ cat0,
                                                       const unsigned short* __restrict__ cat1,
                                                       const unsigned short* __restrict__ cat2,
                                                       const int* __restrict__ batch,
                                                       const float* __restrict__ fc1w,
                                                       const float* __restrict__ fc1b,
                                                       const float* __restrict__ fc2w,
                                                       const float* __restrict__ fc2b,
                                                       float* __restrict__ out) {
    __shared__ int se[2];
    __shared__ float p[192];
    __shared__ float hid[128];
    __shared__ float z[10];
    __shared__ float lse;
    int g = blockIdx.x, tid = threadIdx.x;  // 192 threads
    if (tid < 2) {
        int target = g + tid;
        int lo = 0, hi = N_NODES;
        while (lo < hi) { int mid = (lo + hi) >> 1; if (batch[mid] < target) lo = mid + 1; else hi = mid; }
        se[tid] = lo;
    }
    __syncthreads();
    int s = se[0], e = se[1];
    const unsigned short* plane = (tid < 64) ? cat0 : ((tid < 128) ? cat1 : cat2);
    int col = tid & 63;
    float acc = 0.f;
    for (int r = s; r < e; r++) acc += h2f(plane[(size_t)r * 64 + col]);
    float denom = (e > s) ? (float)(e - s) : 1.0f;
    p[tid] = acc / denom;
    __syncthreads();
    if (tid < MLP_DIM) {
        float a = fc1b[tid];
        for (int k = 0; k < 192; k++) a = fmaf(p[k], fc1w[k * 128 + tid], a);
        hid[tid] = fmaxf(a, 0.f);
    }
    __syncthreads();
    if (tid < N_CLASSES) {
        float a = fc2b[tid];
        for (int k = 0; k < 128; k++) a = fmaf(hid[k], fc2w[k * 10 + tid], a);
        z[tid] = a;
    }
    __syncthreads();
    if (tid == 0) {
        float m = z[0];
        for (int i = 1; i < 10; i++) m = fmaxf(m, z[i]);
        float sm = 0.f;
        for (int i = 0; i < 10; i++) sm += expf(z[i] - m);
        lse = m + logf(sm);
    }
    __syncthreads();
    if (tid < N_CLASSES) out[g * 10 + tid] = z[tid] - lse;
}

// ============================ launch ============================
extern "C" void kernel_launch(void* const* d_in, const int* in_sizes, int n_in,
                              void* d_out, int out_size, void* d_ws, size_t ws_size,
                              hipStream_t stream) {
    (void)in_sizes; (void)n_in; (void)out_size; (void)ws_size;
    const float* x    = (const float*)d_in[0];
    const int*   ei   = (const int*)d_in[1];
    const int*   batch= (const int*)d_in[2];
    const float* fc0w = (const float*)d_in[3];
    const float* fc0b = (const float*)d_in[4];
    const float* fc1w = (const float*)d_in[5];
    const float* fc1b = (const float*)d_in[6];
    const float* fc2w = (const float*)d_in[7];
    const float* fc2b = (const float*)d_in[8];
    const int* src = ei;
    const int* dst = ei + N_EDGES;
    float* out = (float*)d_out;

    char* w = (char*)d_ws;
    size_t off = 0;
    auto alloc = [&](size_t bytes) -> void* {
        void* p = w + off;
        off = (off + bytes + 255) & ~(size_t)255;
        return p;
    };
    const size_t MAX_PAD_EDGES = (size_t)N_EDGES + 16 * (size_t)N_NODES;

    // zeroed-every-launch block: gcur[NB] | bns[3][NSLICE][128]
    char* zbase = (char*)alloc(1024 + 3 * NSLICE * 128 * 4);
    int*   gcur   = (int*)zbase;                     // NB ints (bucket cursors = final counts)
    float* bnsAll = (float*)(zbase + 1024);          // 3 * NSLICE * 128 floats
    const size_t ZBYTES = 1024 + 3 * NSLICE * 128 * 4;

    unsigned short* cat0 = (unsigned short*)alloc((size_t)N_NODES * 64 * 2);  // 6.4 MB/plane (f16)
    unsigned short* cat1 = (unsigned short*)alloc((size_t)N_NODES * 64 * 2);
    unsigned short* cat2 = (unsigned short*)alloc((size_t)N_NODES * 64 * 2);
    unsigned short* h0   = (unsigned short*)alloc((size_t)N_NODES * 64 * 2);  // 6.4 MB (f16)
    unsigned short* Ae   = (unsigned short*)alloc((size_t)N_NODES * 64 * 2);  // 6.4 MB (f16)
    unsigned short* Be   = (unsigned short*)alloc((size_t)N_NODES * 64 * 2);  // 6.4 MB (f16)
    unsigned* keys = (unsigned*)alloc((size_t)NB * CAPB * 4);    // 12.85 MB
    unsigned short* sorted_src = (unsigned short*)alloc(MAX_PAD_EDGES * 2);  // 4.8 MB
    int*   cnt     = (int*)alloc((size_t)N_NODES * 4);
    int*   row_start = (int*)alloc((size_t)(N_NODES + 1) * 4);
    int*   bsum    = (int*)alloc(NB * 4);
    int*   bbase   = (int*)alloc(NB * 4);

    (void)hipMemsetAsync(zbase, 0, ZBYTES, stream);

    // --- two-level counting sort (fixed-capacity buckets): edges -> padded CSR by dst ---
    pass1_kernel<<<(N_EDGES + CHUNK - 1) / CHUNK, 256, 0, stream>>>(src, dst, gcur, keys);
    node_count_kernel<<<NB, 256, 0, stream>>>(keys, gcur, cnt, bsum);
    pscan_kernel<<<1, 256, 0, stream>>>(bsum, bbase, row_start);
    pass2_kernel<<<NB, 256, 0, stream>>>(keys, gcur, cnt, bbase, row_start, sorted_src);

    fc0_mfma_kernel<<<782, 256, 0, stream>>>(x, fc0w, fc0b, h0, bnsAll);

    unsigned short* planes[3] = {cat0, cat1, cat2};
    for (int blk = 0; blk < 3; blk++) {
        const float* g  = (const float*)d_in[9 + 6 * blk];
        const float* bb = (const float*)d_in[10 + 6 * blk];
        const float* w1 = (const float*)d_in[11 + 6 * blk];
        const float* b1 = (const float*)d_in[12 + 6 * blk];
        const float* w2 = (const float*)d_in[13 + 6 * blk];
        const float* b2 = (const float*)d_in[14 + 6 * blk];
        const unsigned short* hsrc = (blk == 0) ? h0 : planes[blk - 1];

        ab_mfma_kernel<<<782, 256, 0, stream>>>(hsrc, bnsAll + blk * NSLICE * 128,
                                                g, bb, w1, b1, Ae, Be);
        edge_mfma_kernel<<<2048, 256, 0, stream>>>(
            Ae, Be, row_start, sorted_src, w2, b2, planes[blk],
            (blk < 2) ? (bnsAll + (blk + 1) * NSLICE * 128) : nullptr);
    }

    poolhead_kernel<<<N_GRAPHS, 192, 0, stream>>>(cat0, cat1, cat2, batch,
                                                  fc1w, fc1b, fc2w, fc2b, out);
}